// Round 16
// baseline (342.058 us; speedup 1.0000x reference)
//
#include <hip/hip_runtime.h>

#define N 256
#define NLINE 8               // lines (waves) per block
#define NB (N / NLINE)        // 32 blocks
#define NT (NLINE * 64)       // 512 threads
#define LAM 0.05f             // step = ALPHA/2
#define TWOLAM (2.0f * LAM)
#define FOURLAM (4.0f * LAM)
#define MAXIT 35
#define TOL 0.01f

// broadcast-read one lane's register (lane index is wave-uniform -> v_readlane)
__device__ __forceinline__ float rlane(float v, int lane) {
    return __int_as_float(__builtin_amdgcn_readlane(__float_as_int(v), lane));
}

// 256-float line distributed over the wave: element k lives in lane (k&63), reg (k>>6)
// -> ballot words are CONTIGUOUS 64-element spans (word w = elements 64w..64w+63)
struct Dist { float r0, r1, r2, r3; };

// branchless fetch: 4 independent readlanes + 2 uniform selects
__device__ __forceinline__ float dfetch(const Dist& d, int k) {
    const int lane = k & 63;
    const int sel = k >> 6;
    float a = rlane(d.r0, lane);
    float b = rlane(d.r1, lane);
    float c = rlane(d.r2, lane);
    float e = rlane(d.r3, lane);
    float ab = (sel & 1) ? b : a;
    float ce = (sel & 1) ? e : c;
    return (sel & 2) ? ce : ab;
}

// O(1) segment flush: o[j] = val for j in [lo, hi]; element j of reg r = 64r + lane
__device__ __forceinline__ void flushseg(Dist& o, int lo, int hi, float val, int lane) {
    const unsigned len = (unsigned)(hi - lo);
    const int base = lane - lo;
    o.r0 = ((unsigned)(base      ) <= len) ? val : o.r0;
    o.r1 = ((unsigned)(base + 64 ) <= len) ? val : o.r1;
    o.r2 = ((unsigned)(base + 128) <= len) ? val : o.r2;
    o.r3 = ((unsigned)(base + 192) <= len) ? val : o.r3;
}

// scalar 4-way select of a 64-bit mask (s_cselect_b64)
__device__ __forceinline__ unsigned long long sel4(unsigned long long a, unsigned long long b,
                                                   unsigned long long c, unsigned long long d, int r) {
    unsigned long long ab = (r & 1) ? b : a;
    unsigned long long cd = (r & 1) ? d : c;
    return (r & 2) ? cd : ab;
}

// Condat's exact 1D TV prox (verified R14 version, unchanged this round).
__device__ void tv1d_scan(const Dist& v, Dist& o, const int lane)
{
    const float lam = LAM, mlam = -LAM, twolam = TWOLAM;

    // ---- per-scan precompute (vectorized) ----
    Dist vnx;                                    // vnx[j] = v[j+1] for j<255; vnx[255] = v[255]
    {
        float a0 = __shfl_down(v.r0, 1), a1 = __shfl_down(v.r1, 1);
        float a2 = __shfl_down(v.r2, 1), a3 = __shfl_down(v.r3, 1);
        const bool hi = (lane == 63);
        vnx.r0 = hi ? rlane(v.r1, 0) : a0;
        vnx.r1 = hi ? rlane(v.r2, 0) : a1;
        vnx.r2 = hi ? rlane(v.r3, 0) : a2;
        vnx.r3 = hi ? v.r3 : a3;                 // element 255 -> v[255] (safe total fetch)
    }
    Dist d;
    d.r0 = vnx.r0 - v.r0;  d.r1 = vnx.r1 - v.r1;
    d.r2 = vnx.r2 - v.r2;  d.r3 = vnx.r3 - v.r3;
    const unsigned lambits = __float_as_uint(lam);
    Dist sl;                                     // sl[j] = sign(d[j]) * lam
    sl.r0 = __uint_as_float((__float_as_uint(d.r0) & 0x80000000u) | lambits);
    sl.r1 = __uint_as_float((__float_as_uint(d.r1) & 0x80000000u) | lambits);
    sl.r2 = __uint_as_float((__float_as_uint(d.r2) & 0x80000000u) | lambits);
    sl.r3 = __uint_as_float((__float_as_uint(d.r3) & 0x80000000u) | lambits);
    Dist slp;                                    // slp[j] = sl[j-1], slp[0] = 0
    {
        float b0 = __shfl_up(sl.r0, 1), b1 = __shfl_up(sl.r1, 1);
        float b2 = __shfl_up(sl.r2, 1), b3 = __shfl_up(sl.r3, 1);
        const bool lo = (lane == 0);
        slp.r0 = lo ? 0.0f : b0;
        slp.r1 = lo ? rlane(sl.r0, 63) : b1;
        slp.r2 = lo ? rlane(sl.r1, 63) : b2;
        slp.r3 = lo ? rlane(sl.r2, 63) : b3;
    }
    Dist e, g;                                   // e[j] = v[j]+sl[j]-slp[j]; g[j] = v[j]-lam-slp[j]
    {
        float t0 = v.r0 - slp.r0, t1 = v.r1 - slp.r1, t2 = v.r2 - slp.r2, t3 = v.r3 - slp.r3;
        e.r0 = t0 + sl.r0;  e.r1 = t1 + sl.r1;  e.r2 = t2 + sl.r2;  e.r3 = t3 + sl.r3;
        g.r0 = t0 - lam;    g.r1 = t1 - lam;    g.r2 = t2 - lam;    g.r3 = t3 - lam;
    }
    const unsigned long long S0 = __ballot(d.r0 < 0.0f);
    const unsigned long long S1 = __ballot(d.r1 < 0.0f);
    const unsigned long long S2 = __ballot(d.r2 < 0.0f);
    const unsigned long long S3 = __ballot(d.r3 < 0.0f);
    const unsigned long long B20 = __ballot(fabsf(d.r0) > TWOLAM);
    const unsigned long long B21 = __ballot(fabsf(d.r1) > TWOLAM);
    const unsigned long long B22 = __ballot(fabsf(d.r2) > TWOLAM);
    const unsigned long long B23 = __ballot(fabsf(d.r3) > TWOLAM);
    const unsigned long long B40 = __ballot(fabsf(d.r0) > FOURLAM);
    const unsigned long long B41 = __ballot(fabsf(d.r1) > FOURLAM);
    const unsigned long long B42 = __ballot(fabsf(d.r2) > FOURLAM);
    const unsigned long long B43 = __ballot(fabsf(d.r3) > FOURLAM);
    // Sprev shifts S by one element across contiguous words
    const unsigned long long Sp0 = (S0 << 1);
    const unsigned long long Sp1 = (S1 << 1) | (S0 >> 63);
    const unsigned long long Sp2 = (S2 << 1) | (S1 >> 63);
    const unsigned long long Sp3 = (S3 << 1) | (S2 >> 63);
    // run-continuation: F = B4 | (B2 & same-sign-as-prev); NF = ~F (element 255 never forced)
    const unsigned long long NF0 = ~(B40 | (B20 & ~(S0 ^ Sp0)));
    const unsigned long long NF1 = ~(B41 | (B21 & ~(S1 ^ Sp1)));
    const unsigned long long NF2 = ~(B42 | (B22 & ~(S2 ^ Sp2)));
    const unsigned long long NF3 = ~((B43 | (B23 & ~(S3 ^ Sp3))) & 0x7FFFFFFFFFFFFFFFull);
    // post-jump trigger masks by ENTRY direction (threshold: same-dir 2lam, opposite 4lam)
    const unsigned long long FNn0 = (S0 & B20) | (~S0 & B40);
    const unsigned long long FNn1 = (S1 & B21) | (~S1 & B41);
    const unsigned long long FNn2 = (S2 & B22) | (~S2 & B42);
    const unsigned long long FNn3 = (S3 & B23) | (~S3 & B43);
    const unsigned long long FNp0 = (~S0 & B20) | (S0 & B40);
    const unsigned long long FNp1 = (~S1 & B21) | (S1 & B41);
    const unsigned long long FNp2 = (~S2 & B22) | (S2 & B42);
    const unsigned long long FNp3 = (~S3 & B23) | (S3 & B43);
    const int initFF = (int)(B40 & 1ull);        // conservative (|d0|>4lam => forced first jump)

    // first non-forced element >= jmin (fast path: same word)
    auto firstnf = [&](int jmin) -> int {
        const int w = jmin >> 6;
        unsigned long long m = sel4(NF0, NF1, NF2, NF3, w) >> (jmin & 63);
        if (m) return jmin + (int)__builtin_ctzll(m);
        unsigned long long m1 = (w < 1) ? NF1 : 0ull;
        unsigned long long m2 = (w < 2) ? NF2 : 0ull;
        if (m1) return 64 + (int)__builtin_ctzll(m1);
        if (m2) return 128 + (int)__builtin_ctzll(m2);
        return 192 + (int)__builtin_ctzll(NF3);  // NF3 bit63 always set -> reachable & nonzero
    };

    auto trigbit = [&](int kk, int neg) -> int {
        const int w = kk >> 6;
        const unsigned long long m = neg ? sel4(FNn0, FNn1, FNn2, FNn3, w)
                                         : sel4(FNp0, FNp1, FNp2, FNp3, w);
        return (int)((m >> (kk & 63)) & 1ull);
    };

    // ---- serial state ----
    int k = 0, k0 = 0, km = 0, kp = 0;
    float umin = lam, umax = mlam;
    const float v0 = rlane(v.r0, 0);
    float vmin = v0 - lam, vmax = v0 + lam;
    float flen = 1.0f;                  // = k - k0 + 1
    float rnext = 0.5f;                 // invariant: rnext == rcp(flen + 1)
    float vn1 = rlane(vnx.r0, 0);       // v[k+1]
    int guard = 0;

    // pre: standard-fresh at k (=k0=km=kp), next jump forced, k <= N-2.
    // EXIT direction = sign(d[k]) is looked up here (NOT the entry direction).
    auto fastfwd = [&]() {
        const int K1 = firstnf(k + 1);                        // first non-forced j > k (<= 255)
        const int sneg = (int)((sel4(S0, S1, S2, S3, k >> 6) >> (k & 63)) & 1ull); // sign(d[k])
        flushseg(o, k, k, sneg ? vmin : vmax, lane);          // first run element
        if (K1 > k + 1) {                                     // (k, K1-1]: closed-form e[j]
            const int lo = k + 1;
            const unsigned len = (unsigned)(K1 - 1 - lo);
            const int base = lane - lo;
            o.r0 = ((unsigned)(base      ) <= len) ? e.r0 : o.r0;
            o.r1 = ((unsigned)(base + 64 ) <= len) ? e.r1 : o.r1;
            o.r2 = ((unsigned)(base + 128) <= len) ? e.r2 : o.r2;
            o.r3 = ((unsigned)(base + 192) <= len) ? e.r3 : o.r3;
        }
        k = K1; k0 = K1; km = K1; kp = K1;                    // fresh at K1, entry sign = S[K1-1]
        vmin = dfetch(g, K1);                                 // = v[K1] - lam - sl[K1-1]
        vmax = vmin + twolam;
        umin = lam; umax = mlam;
        flen = 1.0f; rnext = 0.5f;
        vn1 = dfetch(vnx, K1);                                // shares lane/sel calc with g fetch
    };

    auto do_step = [&]() {
        const float un = umin + vn1 - vmin;
        const float ux = umax + vn1 - vmax;
        const bool neg = un < mlam;
        const bool pos = ux > lam;
        // speculative FF-trigger bits for the fresh landing spot k+1 (off-chain SALU)
        const int wn = (k + 1) >> 6, bn = (k + 1) & 63;
        const int tn = (int)((sel4(FNn0, FNn1, FNn2, FNn3, wn) >> bn) & 1ull);
        const int tp = (int)((sel4(FNp0, FNp1, FNp2, FNp3, wn) >> bn) & 1ull);
        if (__builtin_expect((int)(neg | pos), 1)) {          // JUMP
            const float fval = neg ? vmin : vmax;
            const int   fhi  = neg ? km : kp;
            flushseg(o, k0, fhi, fval, lane);
            const int k0n = fhi + 1;
            float vstar;
            int trig;
            if (__builtin_expect((int)(k0n <= k), 0)) {       // rewind (rare)
                vstar = dfetch(v, k0n);
                trig = trigbit(k0n, (int)neg);
            } else {                                          // fresh: renames + precomputed trig
                vstar = vn1;
                trig = neg ? tn : tp;
            }
            k = k0n; k0 = k0n; km = k0n; kp = k0n;
            vmin = neg ? vstar : vstar - twolam;
            vmax = vmin + twolam;
            umin = lam; umax = mlam;
            flen = 1.0f; rnext = 0.5f;
            if (k < N - 1 && trig) {
                fastfwd();                                    // run of guaranteed jumps
            } else {
                vn1 = dfetch(vnx, k);                         // = v[k+1] (total, clamp-free)
            }
        } else {                                              // no jump (predicated)
            k++;
            const float r = rnext;                            // = rcp(k - k0 + 1), precomputed
            flen += 1.0f;
            const bool cmin = (un >= lam);
            const bool cmax = (ux <= mlam);
            vmin = cmin ? fmaf(un - lam, r, vmin) : vmin;
            km   = cmin ? k : km;
            umin = cmin ? lam : un;
            vmax = cmax ? fmaf(ux + lam, r, vmax) : vmax;
            kp   = cmax ? k : kp;
            umax = cmax ? mlam : ux;
            vn1 = dfetch(vnx, k);                             // = v[k+1] (total, clamp-free)
            rnext = __builtin_amdgcn_rcpf(flen + 1.0f);       // off-chain for next step
        }
    };

    if (initFF) fastfwd();

    for (;;) {
        while (k < N - 1) {
            if (++guard > 2000) return; // provably terminates; belt+suspenders
            do_step();
            if (k >= N - 1) break;
            do_step();
        }
        // boundary resolution at k == N-1 (verbatim semantics from verified R2/R6)
        for (;;) {
            if (++guard > 4000) return;
            if (umin < 0.0f) {
                flushseg(o, k0, km, vmin, lane);
                k0 = km + 1;
                if (k0 > N - 1) return;
                km = k = k0;
                vmin = dfetch(v, k0);
                umin = lam;
                umax = vmin + lam - vmax;
                flen = 1.0f;
            } else if (umax > 0.0f) {
                flushseg(o, k0, kp, vmax, lane);
                k0 = kp + 1;
                if (k0 > N - 1) return;
                kp = k = k0;
                vmax = dfetch(v, k0);
                umax = mlam;
                umin = vmax - lam - vmin;
                flen = 1.0f;
            } else {
                vmin += umin / flen;
                flushseg(o, k0, k, vmin, lane);
                return;
            }
            if (k != N - 1) break;
        }
        rnext = 0.5f;                                         // flen == 1 here
        vn1 = dfetch(vnx, k);                                 // = v[k+1]
    }
}

// flag-array grid barrier (32 blocks) with split release/acquire fences and hot
// poll. Block b stores flags[b]=seq; wave 0's 64 lanes poll flags[t&31] (each
// flag read twice) with one coalesced load. Needs co-residency (coop launch),
// flags zeroed at launch, seq strictly increasing.
__device__ __forceinline__ void gridbar(unsigned* flags, unsigned seq, int t) {
    __syncthreads();                                          // all stores issued+drained
    __builtin_amdgcn_fence(__ATOMIC_RELEASE, "agent");        // L2 writeback only
    if (t == 0)
        __hip_atomic_store(&flags[blockIdx.x], seq, __ATOMIC_RELAXED, __HIP_MEMORY_SCOPE_AGENT);
    if (t < 64) {
        for (;;) {
            unsigned f = __hip_atomic_load(&flags[t & (NB - 1)], __ATOMIC_RELAXED, __HIP_MEMORY_SCOPE_AGENT);
            if (__all((int)(f >= seq))) break;
        }
    }
    __builtin_amdgcn_fence(__ATOMIC_ACQUIRE, "agent");        // L2 invalidate only
    __syncthreads();
}

// Douglas-Rachford TV2D: wave w of block b owns column (8b+w) in phase 1 and row
// (8b+w) in phase 2. p, q persist in registers across iterations. Convergence
// decision is one-iteration-delayed and overlapped with the next column loads:
// the column phase never writes xw, so breaking before the row phase leaves
// d_out == x2 of the converged iteration (exactly the reference's output).
__global__ __launch_bounds__(NT) void tv2d_coop(const float* __restrict__ X,
                                                float* __restrict__ xw,     // = d_out
                                                float* __restrict__ y,
                                                unsigned* __restrict__ flags,  // [NB]
                                                unsigned* __restrict__ bm)     // [NB] per-block max
{
    const int t = threadIdx.x;
    const int lane = t & 63;
    const int wave = t >> 6;
    const int line = blockIdx.x * NLINE + wave;
    __shared__ unsigned s_acc;
    __shared__ int s_dec;
    if (t == 0) s_acc = 0u;

    Dist p = {0.f, 0.f, 0.f, 0.f};
    Dist q = {0.f, 0.f, 0.f, 0.f};

    for (int it = 0; it < MAXIT; ++it) {
        // ---- column phase: y = prox(x + p) on column `line`; p = v - y ----
        const float* xs = (it == 0) ? X : xw;
        const float* col = xs + line;
        float c0 = col[(lane      ) * N];      // loads issue first...
        float c1 = col[(lane + 64 ) * N];
        float c2 = col[(lane + 128) * N];
        float c3 = col[(lane + 192) * N];
        if (it > 0) {                           // ...decision for it-1 overlaps their latency
            if (t < 64) {
                unsigned m = __hip_atomic_load(&bm[t & (NB - 1)], __ATOMIC_RELAXED, __HIP_MEMORY_SCOPE_AGENT);
                #pragma unroll
                for (int off = 32; off > 0; off >>= 1) {
                    unsigned mm = __shfl_xor(m, off);
                    m = (mm > m) ? mm : m;      // am>=0: uint order == float order
                }
                if (t == 0) s_dec = (__uint_as_float(m) < TOL) ? 1 : 0;
            }
            __syncthreads();
            if (s_dec) break;                   // xw holds x2 of it-1 (reference output)
        }
        Dist v, o;
        v.r0 = c0 + p.r0;
        v.r1 = c1 + p.r1;
        v.r2 = c2 + p.r2;
        v.r3 = c3 + p.r3;
        tv1d_scan(v, o, lane);
        p.r0 = v.r0 - o.r0;  p.r1 = v.r1 - o.r1;
        p.r2 = v.r2 - o.r2;  p.r3 = v.r3 - o.r3;
        float* ycol = y + line;
        ycol[(lane      ) * N] = o.r0;
        ycol[(lane + 64 ) * N] = o.r1;
        ycol[(lane + 128) * N] = o.r2;
        ycol[(lane + 192) * N] = o.r3;
        gridbar(flags, 2u * (unsigned)it + 1u, t);

        // ---- row phase: x2 = prox(y + q) on row `line`; q = v - x2; acc = max|y-x2| ----
        const float* yr = y + line * N;
        float y0 = yr[lane      ];
        float y1 = yr[lane + 64 ];
        float y2 = yr[lane + 128];
        float y3 = yr[lane + 192];
        Dist w, o2;
        w.r0 = y0 + q.r0;
        w.r1 = y1 + q.r1;
        w.r2 = y2 + q.r2;
        w.r3 = y3 + q.r3;
        tv1d_scan(w, o2, lane);
        float d0 = y0 - o2.r0;    // y - x2
        float d1 = y1 - o2.r1;
        float d2 = y2 - o2.r2;
        float d3 = y3 - o2.r3;
        q.r0 = w.r0 - o2.r0;  q.r1 = w.r1 - o2.r1;
        q.r2 = w.r2 - o2.r2;  q.r3 = w.r3 - o2.r3;
        float* xr = xw + line * N;
        xr[lane      ] = o2.r0;
        xr[lane + 64 ] = o2.r1;
        xr[lane + 128] = o2.r2;
        xr[lane + 192] = o2.r3;

        float am = fmaxf(fmaxf(fabsf(d0), fabsf(d1)), fmaxf(fabsf(d2), fabsf(d3)));
        #pragma unroll
        for (int off = 32; off > 0; off >>= 1)
            am = fmaxf(am, __shfl_xor(am, off));
        if (lane == 0) atomicMax(&s_acc, __float_as_uint(am));   // LDS atomic, 8/block

        // ---- barrier 2 with per-block max payload (no decision tail) ----
        __syncthreads();                                          // s_acc complete
        if (t == 0) {
            __hip_atomic_store(&bm[blockIdx.x], s_acc, __ATOMIC_RELAXED, __HIP_MEMORY_SCOPE_AGENT);
            s_acc = 0u;                                           // reset for next iteration
        }
        gridbar(flags, 2u * (unsigned)it + 2u, t);                // release covers bm + x2 writes
    }
}

extern "C" void kernel_launch(void* const* d_in, const int* in_sizes, int n_in,
                              void* d_out, int out_size, void* d_ws, size_t ws_size,
                              hipStream_t stream) {
    const float* X = (const float*)d_in[0];
    float* xw = (float*)d_out;
    float* y = (float*)d_ws;
    unsigned* flags = (unsigned*)((char*)d_ws + (size_t)N * N * sizeof(float));
    unsigned* bm = flags + 64;                 // separate 256B line from flags
    // zero the flag array before the kernel (capture-legal); bm written before read
    (void)hipMemsetAsync((void*)flags, 0, NB * sizeof(unsigned), stream);
    void* args[] = { (void*)&X, (void*)&xw, (void*)&y, (void*)&flags, (void*)&bm };
    (void)hipLaunchCooperativeKernel((void*)tv2d_coop, dim3(NB), dim3(NT), args, 0, stream);
}

// Round 17
// 319.011 us; speedup vs baseline: 1.0722x; 1.0722x over previous
//
#include <hip/hip_runtime.h>

#define N 256
#define NLINE 4               // lines (waves) per block
#define NB (N / NLINE)        // 64 blocks
#define NT (NLINE * 64)       // 256 threads
#define LAM 0.05f             // step = ALPHA/2
#define TWOLAM (2.0f * LAM)
#define FOURLAM (4.0f * LAM)
#define MAXIT 35
#define TOL 0.01f

// broadcast-read one lane's register (lane index is wave-uniform -> v_readlane)
__device__ __forceinline__ float rlane(float v, int lane) {
    return __int_as_float(__builtin_amdgcn_readlane(__float_as_int(v), lane));
}

// 256-float line distributed over the wave: element k lives in lane (k&63), reg (k>>6)
// -> ballot words are CONTIGUOUS 64-element spans (word w = elements 64w..64w+63)
struct Dist { float r0, r1, r2, r3; };

// branchless fetch: 4 independent readlanes + 2 uniform selects
__device__ __forceinline__ float dfetch(const Dist& d, int k) {
    const int lane = k & 63;
    const int sel = k >> 6;
    float a = rlane(d.r0, lane);
    float b = rlane(d.r1, lane);
    float c = rlane(d.r2, lane);
    float e = rlane(d.r3, lane);
    float ab = (sel & 1) ? b : a;
    float ce = (sel & 1) ? e : c;
    return (sel & 2) ? ce : ab;
}

// O(1) segment flush: o[j] = val for j in [lo, hi]; element j of reg r = 64r + lane
__device__ __forceinline__ void flushseg(Dist& o, int lo, int hi, float val, int lane) {
    const unsigned len = (unsigned)(hi - lo);
    const int base = lane - lo;
    o.r0 = ((unsigned)(base      ) <= len) ? val : o.r0;
    o.r1 = ((unsigned)(base + 64 ) <= len) ? val : o.r1;
    o.r2 = ((unsigned)(base + 128) <= len) ? val : o.r2;
    o.r3 = ((unsigned)(base + 192) <= len) ? val : o.r3;
}

// scalar 4-way select of a 64-bit mask (s_cselect_b64)
__device__ __forceinline__ unsigned long long sel4(unsigned long long a, unsigned long long b,
                                                   unsigned long long c, unsigned long long d, int r) {
    unsigned long long ab = (r & 1) ? b : a;
    unsigned long long cd = (r & 1) ? d : c;
    return (r & 2) ? cd : ab;
}

// Condat's exact 1D TV prox (verified R14 version, unchanged this round).
__device__ void tv1d_scan(const Dist& v, Dist& o, const int lane)
{
    const float lam = LAM, mlam = -LAM, twolam = TWOLAM;

    // ---- per-scan precompute (vectorized) ----
    Dist vnx;                                    // vnx[j] = v[j+1] for j<255; vnx[255] = v[255]
    {
        float a0 = __shfl_down(v.r0, 1), a1 = __shfl_down(v.r1, 1);
        float a2 = __shfl_down(v.r2, 1), a3 = __shfl_down(v.r3, 1);
        const bool hi = (lane == 63);
        vnx.r0 = hi ? rlane(v.r1, 0) : a0;
        vnx.r1 = hi ? rlane(v.r2, 0) : a1;
        vnx.r2 = hi ? rlane(v.r3, 0) : a2;
        vnx.r3 = hi ? v.r3 : a3;                 // element 255 -> v[255] (safe total fetch)
    }
    Dist d;
    d.r0 = vnx.r0 - v.r0;  d.r1 = vnx.r1 - v.r1;
    d.r2 = vnx.r2 - v.r2;  d.r3 = vnx.r3 - v.r3;
    const unsigned lambits = __float_as_uint(lam);
    Dist sl;                                     // sl[j] = sign(d[j]) * lam
    sl.r0 = __uint_as_float((__float_as_uint(d.r0) & 0x80000000u) | lambits);
    sl.r1 = __uint_as_float((__float_as_uint(d.r1) & 0x80000000u) | lambits);
    sl.r2 = __uint_as_float((__float_as_uint(d.r2) & 0x80000000u) | lambits);
    sl.r3 = __uint_as_float((__float_as_uint(d.r3) & 0x80000000u) | lambits);
    Dist slp;                                    // slp[j] = sl[j-1], slp[0] = 0
    {
        float b0 = __shfl_up(sl.r0, 1), b1 = __shfl_up(sl.r1, 1);
        float b2 = __shfl_up(sl.r2, 1), b3 = __shfl_up(sl.r3, 1);
        const bool lo = (lane == 0);
        slp.r0 = lo ? 0.0f : b0;
        slp.r1 = lo ? rlane(sl.r0, 63) : b1;
        slp.r2 = lo ? rlane(sl.r1, 63) : b2;
        slp.r3 = lo ? rlane(sl.r2, 63) : b3;
    }
    Dist e, g;                                   // e[j] = v[j]+sl[j]-slp[j]; g[j] = v[j]-lam-slp[j]
    {
        float t0 = v.r0 - slp.r0, t1 = v.r1 - slp.r1, t2 = v.r2 - slp.r2, t3 = v.r3 - slp.r3;
        e.r0 = t0 + sl.r0;  e.r1 = t1 + sl.r1;  e.r2 = t2 + sl.r2;  e.r3 = t3 + sl.r3;
        g.r0 = t0 - lam;    g.r1 = t1 - lam;    g.r2 = t2 - lam;    g.r3 = t3 - lam;
    }
    const unsigned long long S0 = __ballot(d.r0 < 0.0f);
    const unsigned long long S1 = __ballot(d.r1 < 0.0f);
    const unsigned long long S2 = __ballot(d.r2 < 0.0f);
    const unsigned long long S3 = __ballot(d.r3 < 0.0f);
    const unsigned long long B20 = __ballot(fabsf(d.r0) > TWOLAM);
    const unsigned long long B21 = __ballot(fabsf(d.r1) > TWOLAM);
    const unsigned long long B22 = __ballot(fabsf(d.r2) > TWOLAM);
    const unsigned long long B23 = __ballot(fabsf(d.r3) > TWOLAM);
    const unsigned long long B40 = __ballot(fabsf(d.r0) > FOURLAM);
    const unsigned long long B41 = __ballot(fabsf(d.r1) > FOURLAM);
    const unsigned long long B42 = __ballot(fabsf(d.r2) > FOURLAM);
    const unsigned long long B43 = __ballot(fabsf(d.r3) > FOURLAM);
    // Sprev shifts S by one element across contiguous words
    const unsigned long long Sp0 = (S0 << 1);
    const unsigned long long Sp1 = (S1 << 1) | (S0 >> 63);
    const unsigned long long Sp2 = (S2 << 1) | (S1 >> 63);
    const unsigned long long Sp3 = (S3 << 1) | (S2 >> 63);
    // run-continuation: F = B4 | (B2 & same-sign-as-prev); NF = ~F (element 255 never forced)
    const unsigned long long NF0 = ~(B40 | (B20 & ~(S0 ^ Sp0)));
    const unsigned long long NF1 = ~(B41 | (B21 & ~(S1 ^ Sp1)));
    const unsigned long long NF2 = ~(B42 | (B22 & ~(S2 ^ Sp2)));
    const unsigned long long NF3 = ~((B43 | (B23 & ~(S3 ^ Sp3))) & 0x7FFFFFFFFFFFFFFFull);
    // post-jump trigger masks by ENTRY direction (threshold: same-dir 2lam, opposite 4lam)
    const unsigned long long FNn0 = (S0 & B20) | (~S0 & B40);
    const unsigned long long FNn1 = (S1 & B21) | (~S1 & B41);
    const unsigned long long FNn2 = (S2 & B22) | (~S2 & B42);
    const unsigned long long FNn3 = (S3 & B23) | (~S3 & B43);
    const unsigned long long FNp0 = (~S0 & B20) | (S0 & B40);
    const unsigned long long FNp1 = (~S1 & B21) | (S1 & B41);
    const unsigned long long FNp2 = (~S2 & B22) | (S2 & B42);
    const unsigned long long FNp3 = (~S3 & B23) | (S3 & B43);
    const int initFF = (int)(B40 & 1ull);        // conservative (|d0|>4lam => forced first jump)

    // first non-forced element >= jmin (fast path: same word)
    auto firstnf = [&](int jmin) -> int {
        const int w = jmin >> 6;
        unsigned long long m = sel4(NF0, NF1, NF2, NF3, w) >> (jmin & 63);
        if (m) return jmin + (int)__builtin_ctzll(m);
        unsigned long long m1 = (w < 1) ? NF1 : 0ull;
        unsigned long long m2 = (w < 2) ? NF2 : 0ull;
        if (m1) return 64 + (int)__builtin_ctzll(m1);
        if (m2) return 128 + (int)__builtin_ctzll(m2);
        return 192 + (int)__builtin_ctzll(NF3);  // NF3 bit63 always set -> reachable & nonzero
    };

    auto trigbit = [&](int kk, int neg) -> int {
        const int w = kk >> 6;
        const unsigned long long m = neg ? sel4(FNn0, FNn1, FNn2, FNn3, w)
                                         : sel4(FNp0, FNp1, FNp2, FNp3, w);
        return (int)((m >> (kk & 63)) & 1ull);
    };

    // ---- serial state ----
    int k = 0, k0 = 0, km = 0, kp = 0;
    float umin = lam, umax = mlam;
    const float v0 = rlane(v.r0, 0);
    float vmin = v0 - lam, vmax = v0 + lam;
    float flen = 1.0f;                  // = k - k0 + 1
    float rnext = 0.5f;                 // invariant: rnext == rcp(flen + 1)
    float vn1 = rlane(vnx.r0, 0);       // v[k+1]
    int guard = 0;

    // pre: standard-fresh at k (=k0=km=kp), next jump forced, k <= N-2.
    // EXIT direction = sign(d[k]) is looked up here (NOT the entry direction).
    auto fastfwd = [&]() {
        const int K1 = firstnf(k + 1);                        // first non-forced j > k (<= 255)
        const int sneg = (int)((sel4(S0, S1, S2, S3, k >> 6) >> (k & 63)) & 1ull); // sign(d[k])
        flushseg(o, k, k, sneg ? vmin : vmax, lane);          // first run element
        if (K1 > k + 1) {                                     // (k, K1-1]: closed-form e[j]
            const int lo = k + 1;
            const unsigned len = (unsigned)(K1 - 1 - lo);
            const int base = lane - lo;
            o.r0 = ((unsigned)(base      ) <= len) ? e.r0 : o.r0;
            o.r1 = ((unsigned)(base + 64 ) <= len) ? e.r1 : o.r1;
            o.r2 = ((unsigned)(base + 128) <= len) ? e.r2 : o.r2;
            o.r3 = ((unsigned)(base + 192) <= len) ? e.r3 : o.r3;
        }
        k = K1; k0 = K1; km = K1; kp = K1;                    // fresh at K1, entry sign = S[K1-1]
        vmin = dfetch(g, K1);                                 // = v[K1] - lam - sl[K1-1]
        vmax = vmin + twolam;
        umin = lam; umax = mlam;
        flen = 1.0f; rnext = 0.5f;
        vn1 = dfetch(vnx, K1);                                // shares lane/sel calc with g fetch
    };

    auto do_step = [&]() {
        const float un = umin + vn1 - vmin;
        const float ux = umax + vn1 - vmax;
        const bool neg = un < mlam;
        const bool pos = ux > lam;
        // speculative FF-trigger bits for the fresh landing spot k+1 (off-chain SALU)
        const int wn = (k + 1) >> 6, bn = (k + 1) & 63;
        const int tn = (int)((sel4(FNn0, FNn1, FNn2, FNn3, wn) >> bn) & 1ull);
        const int tp = (int)((sel4(FNp0, FNp1, FNp2, FNp3, wn) >> bn) & 1ull);
        if (__builtin_expect((int)(neg | pos), 1)) {          // JUMP
            const float fval = neg ? vmin : vmax;
            const int   fhi  = neg ? km : kp;
            flushseg(o, k0, fhi, fval, lane);
            const int k0n = fhi + 1;
            float vstar;
            int trig;
            if (__builtin_expect((int)(k0n <= k), 0)) {       // rewind (rare)
                vstar = dfetch(v, k0n);
                trig = trigbit(k0n, (int)neg);
            } else {                                          // fresh: renames + precomputed trig
                vstar = vn1;
                trig = neg ? tn : tp;
            }
            k = k0n; k0 = k0n; km = k0n; kp = k0n;
            vmin = neg ? vstar : vstar - twolam;
            vmax = vmin + twolam;
            umin = lam; umax = mlam;
            flen = 1.0f; rnext = 0.5f;
            if (k < N - 1 && trig) {
                fastfwd();                                    // run of guaranteed jumps
            } else {
                vn1 = dfetch(vnx, k);                         // = v[k+1] (total, clamp-free)
            }
        } else {                                              // no jump (predicated)
            k++;
            const float r = rnext;                            // = rcp(k - k0 + 1), precomputed
            flen += 1.0f;
            const bool cmin = (un >= lam);
            const bool cmax = (ux <= mlam);
            vmin = cmin ? fmaf(un - lam, r, vmin) : vmin;
            km   = cmin ? k : km;
            umin = cmin ? lam : un;
            vmax = cmax ? fmaf(ux + lam, r, vmax) : vmax;
            kp   = cmax ? k : kp;
            umax = cmax ? mlam : ux;
            vn1 = dfetch(vnx, k);                             // = v[k+1] (total, clamp-free)
            rnext = __builtin_amdgcn_rcpf(flen + 1.0f);       // off-chain for next step
        }
    };

    if (initFF) fastfwd();

    for (;;) {
        while (k < N - 1) {
            if (++guard > 2000) return; // provably terminates; belt+suspenders
            do_step();
            if (k >= N - 1) break;
            do_step();
        }
        // boundary resolution at k == N-1 (verbatim semantics from verified R2/R6)
        for (;;) {
            if (++guard > 4000) return;
            if (umin < 0.0f) {
                flushseg(o, k0, km, vmin, lane);
                k0 = km + 1;
                if (k0 > N - 1) return;
                km = k = k0;
                vmin = dfetch(v, k0);
                umin = lam;
                umax = vmin + lam - vmax;
                flen = 1.0f;
            } else if (umax > 0.0f) {
                flushseg(o, k0, kp, vmax, lane);
                k0 = kp + 1;
                if (k0 > N - 1) return;
                kp = k = k0;
                vmax = dfetch(v, k0);
                umax = mlam;
                umin = vmax - lam - vmin;
                flen = 1.0f;
            } else {
                vmin += umin / flen;
                flushseg(o, k0, k, vmin, lane);
                return;
            }
            if (k != N - 1) break;
        }
        rnext = 0.5f;                                         // flen == 1 here
        vn1 = dfetch(vnx, k);                                 // = v[k+1]
    }
}

// flag-array grid barrier with split release/acquire fences and hot poll (R15).
__device__ __forceinline__ void gridbar(unsigned* flags, unsigned seq, int t) {
    __syncthreads();                                          // all stores issued+drained
    __builtin_amdgcn_fence(__ATOMIC_RELEASE, "agent");        // L2 writeback only
    if (t == 0)
        __hip_atomic_store(&flags[blockIdx.x], seq, __ATOMIC_RELAXED, __HIP_MEMORY_SCOPE_AGENT);
    if (t < 64) {
        for (;;) {
            unsigned f = __hip_atomic_load(&flags[t], __ATOMIC_RELAXED, __HIP_MEMORY_SCOPE_AGENT);
            if (__all((int)(f >= seq))) break;
        }
    }
    __builtin_amdgcn_fence(__ATOMIC_ACQUIRE, "agent");        // L2 invalidate only
    __syncthreads();
}

// Douglas-Rachford TV2D. Wave w of block b owns column (4b+w) in phase 1 and row
// (4b+w) in phase 2. Global I/O is coalesced via float4 row-chunks + an LDS
// transpose tile (pad 5 -> conflict-free); y is stored TRANSPOSED (yT[line][e],
// coalesced), and the row phase re-transposes it through LDS. Convergence
// decision is one-iteration-delayed and overlapped with the column loads.
__global__ __launch_bounds__(NT) void tv2d_coop(const float* __restrict__ X,
                                                float* __restrict__ xw,     // = d_out
                                                float* __restrict__ y,      // holds yT
                                                unsigned* __restrict__ flags,  // [NB]
                                                unsigned* __restrict__ bm)     // [NB] per-block max
{
    const int t = threadIdx.x;
    const int lane = t & 63;
    const int wave = t >> 6;
    const int line = blockIdx.x * NLINE + wave;
    const int col4 = 4 * blockIdx.x;             // block's 4-column / 4-row group
    __shared__ float tile[N * 5];                // transpose tile, stride-5 padded
    __shared__ unsigned s_acc;
    __shared__ int s_dec;
    if (t == 0) s_acc = 0u;

    Dist p = {0.f, 0.f, 0.f, 0.f};
    Dist q = {0.f, 0.f, 0.f, 0.f};

    for (int it = 0; it < MAXIT; ++it) {
        // ---- column phase: y = prox(x + p) on column `line`; p = v - y ----
        const float* xs = (it == 0) ? X : xw;
        const float4 xc = *(const float4*)(xs + t * N + col4);  // row-chunk, issues early
        if (it > 0) {                           // decision for it-1 overlaps load latency
            if (t < 64) {
                unsigned m = __hip_atomic_load(&bm[t], __ATOMIC_RELAXED, __HIP_MEMORY_SCOPE_AGENT);
                #pragma unroll
                for (int off = 32; off > 0; off >>= 1) {
                    unsigned mm = __shfl_xor(m, off);
                    m = (mm > m) ? mm : m;      // am>=0: uint order == float order
                }
                if (t == 0) s_dec = (__uint_as_float(m) < TOL) ? 1 : 0;
            }
            __syncthreads();
            if (s_dec) break;                   // xw holds x2 of it-1 (reference output)
        }
        tile[t * 5 + 0] = xc.x;                 // transpose deposit: tile[row][c]
        tile[t * 5 + 1] = xc.y;
        tile[t * 5 + 2] = xc.z;
        tile[t * 5 + 3] = xc.w;
        __syncthreads();
        Dist v, o;
        v.r0 = tile[(lane      ) * 5 + wave] + p.r0;   // column `line` from LDS
        v.r1 = tile[(lane + 64 ) * 5 + wave] + p.r1;
        v.r2 = tile[(lane + 128) * 5 + wave] + p.r2;
        v.r3 = tile[(lane + 192) * 5 + wave] + p.r3;
        tv1d_scan(v, o, lane);
        p.r0 = v.r0 - o.r0;  p.r1 = v.r1 - o.r1;
        p.r2 = v.r2 - o.r2;  p.r3 = v.r3 - o.r3;
        float* yt = y + line * N;               // y stored TRANSPOSED -> coalesced
        yt[lane      ] = o.r0;
        yt[lane + 64 ] = o.r1;
        yt[lane + 128] = o.r2;
        yt[lane + 192] = o.r3;
        gridbar(flags, 2u * (unsigned)it + 1u, t);

        // ---- row phase: x2 = prox(y + q) on row `line`; q = v - x2; acc = max|y-x2| ----
        // row r of y == yT[*][r]; block needs yT[j][col4..col4+3] -> float4 chunks
        const float4 yc = *(const float4*)(y + t * N + col4);
        tile[t * 5 + 0] = yc.x;                 // tile[j][c] = y[col4+c][j]
        tile[t * 5 + 1] = yc.y;
        tile[t * 5 + 2] = yc.z;
        tile[t * 5 + 3] = yc.w;
        __syncthreads();
        float y0 = tile[(lane      ) * 5 + wave];      // row `line` elements
        float y1 = tile[(lane + 64 ) * 5 + wave];
        float y2 = tile[(lane + 128) * 5 + wave];
        float y3 = tile[(lane + 192) * 5 + wave];
        Dist w, o2;
        w.r0 = y0 + q.r0;
        w.r1 = y1 + q.r1;
        w.r2 = y2 + q.r2;
        w.r3 = y3 + q.r3;
        tv1d_scan(w, o2, lane);
        float d0 = y0 - o2.r0;    // y - x2
        float d1 = y1 - o2.r1;
        float d2 = y2 - o2.r2;
        float d3 = y3 - o2.r3;
        q.r0 = w.r0 - o2.r0;  q.r1 = w.r1 - o2.r1;
        q.r2 = w.r2 - o2.r2;  q.r3 = w.r3 - o2.r3;
        float* xr = xw + line * N;              // row-major, coalesced
        xr[lane      ] = o2.r0;
        xr[lane + 64 ] = o2.r1;
        xr[lane + 128] = o2.r2;
        xr[lane + 192] = o2.r3;

        float am = fmaxf(fmaxf(fabsf(d0), fabsf(d1)), fmaxf(fabsf(d2), fabsf(d3)));
        #pragma unroll
        for (int off = 32; off > 0; off >>= 1)
            am = fmaxf(am, __shfl_xor(am, off));
        if (lane == 0) atomicMax(&s_acc, __float_as_uint(am));   // LDS atomic, 4/block

        // ---- barrier 2 with per-block max payload (no decision tail) ----
        __syncthreads();                                          // s_acc complete
        if (t == 0) {
            __hip_atomic_store(&bm[blockIdx.x], s_acc, __ATOMIC_RELAXED, __HIP_MEMORY_SCOPE_AGENT);
            s_acc = 0u;                                           // reset for next iteration
        }
        gridbar(flags, 2u * (unsigned)it + 2u, t);                // release covers bm + x2 writes
    }
}

extern "C" void kernel_launch(void* const* d_in, const int* in_sizes, int n_in,
                              void* d_out, int out_size, void* d_ws, size_t ws_size,
                              hipStream_t stream) {
    const float* X = (const float*)d_in[0];
    float* xw = (float*)d_out;
    float* y = (float*)d_ws;
    unsigned* flags = (unsigned*)((char*)d_ws + (size_t)N * N * sizeof(float));
    unsigned* bm = flags + 64;
    // zero the flag array before the kernel (capture-legal); bm written before read
    (void)hipMemsetAsync((void*)flags, 0, NB * sizeof(unsigned), stream);
    void* args[] = { (void*)&X, (void*)&xw, (void*)&y, (void*)&flags, (void*)&bm };
    (void)hipLaunchCooperativeKernel((void*)tv2d_coop, dim3(NB), dim3(NT), args, 0, stream);
}

// Round 18
// 304.673 us; speedup vs baseline: 1.1227x; 1.0471x over previous
//
#include <hip/hip_runtime.h>

#define N 256
#define NLINE 4               // lines (waves) per block
#define NB (N / NLINE)        // 64 blocks
#define NT (NLINE * 64)       // 256 threads
#define LAM 0.05f             // step = ALPHA/2
#define TWOLAM (2.0f * LAM)
#define FOURLAM (4.0f * LAM)
#define MAXIT 35
#define TOL 0.01f
#define SLOTSTRIDE 16         // uint64 elements -> 128 B per block slot (own L3 line)

// broadcast-read one lane's register (lane index is wave-uniform -> v_readlane)
__device__ __forceinline__ float rlane(float v, int lane) {
    return __int_as_float(__builtin_amdgcn_readlane(__float_as_int(v), lane));
}

// 256-float line distributed over the wave: element k lives in lane (k&63), reg (k>>6)
// -> ballot words are CONTIGUOUS 64-element spans (word w = elements 64w..64w+63)
struct Dist { float r0, r1, r2, r3; };

// branchless fetch: 4 independent readlanes + 2 uniform selects
__device__ __forceinline__ float dfetch(const Dist& d, int k) {
    const int lane = k & 63;
    const int sel = k >> 6;
    float a = rlane(d.r0, lane);
    float b = rlane(d.r1, lane);
    float c = rlane(d.r2, lane);
    float e = rlane(d.r3, lane);
    float ab = (sel & 1) ? b : a;
    float ce = (sel & 1) ? e : c;
    return (sel & 2) ? ce : ab;
}

// O(1) segment flush: o[j] = val for j in [lo, hi]; element j of reg r = 64r + lane
__device__ __forceinline__ void flushseg(Dist& o, int lo, int hi, float val, int lane) {
    const unsigned len = (unsigned)(hi - lo);
    const int base = lane - lo;
    o.r0 = ((unsigned)(base      ) <= len) ? val : o.r0;
    o.r1 = ((unsigned)(base + 64 ) <= len) ? val : o.r1;
    o.r2 = ((unsigned)(base + 128) <= len) ? val : o.r2;
    o.r3 = ((unsigned)(base + 192) <= len) ? val : o.r3;
}

// scalar 4-way select of a 64-bit mask (s_cselect_b64)
__device__ __forceinline__ unsigned long long sel4(unsigned long long a, unsigned long long b,
                                                   unsigned long long c, unsigned long long d, int r) {
    unsigned long long ab = (r & 1) ? b : a;
    unsigned long long cd = (r & 1) ? d : c;
    return (r & 2) ? cd : ab;
}

// Condat's exact 1D TV prox (verified R14 version, unchanged this round).
__device__ void tv1d_scan(const Dist& v, Dist& o, const int lane)
{
    const float lam = LAM, mlam = -LAM, twolam = TWOLAM;

    // ---- per-scan precompute (vectorized) ----
    Dist vnx;                                    // vnx[j] = v[j+1] for j<255; vnx[255] = v[255]
    {
        float a0 = __shfl_down(v.r0, 1), a1 = __shfl_down(v.r1, 1);
        float a2 = __shfl_down(v.r2, 1), a3 = __shfl_down(v.r3, 1);
        const bool hi = (lane == 63);
        vnx.r0 = hi ? rlane(v.r1, 0) : a0;
        vnx.r1 = hi ? rlane(v.r2, 0) : a1;
        vnx.r2 = hi ? rlane(v.r3, 0) : a2;
        vnx.r3 = hi ? v.r3 : a3;                 // element 255 -> v[255] (safe total fetch)
    }
    Dist d;
    d.r0 = vnx.r0 - v.r0;  d.r1 = vnx.r1 - v.r1;
    d.r2 = vnx.r2 - v.r2;  d.r3 = vnx.r3 - v.r3;
    const unsigned lambits = __float_as_uint(lam);
    Dist sl;                                     // sl[j] = sign(d[j]) * lam
    sl.r0 = __uint_as_float((__float_as_uint(d.r0) & 0x80000000u) | lambits);
    sl.r1 = __uint_as_float((__float_as_uint(d.r1) & 0x80000000u) | lambits);
    sl.r2 = __uint_as_float((__float_as_uint(d.r2) & 0x80000000u) | lambits);
    sl.r3 = __uint_as_float((__float_as_uint(d.r3) & 0x80000000u) | lambits);
    Dist slp;                                    // slp[j] = sl[j-1], slp[0] = 0
    {
        float b0 = __shfl_up(sl.r0, 1), b1 = __shfl_up(sl.r1, 1);
        float b2 = __shfl_up(sl.r2, 1), b3 = __shfl_up(sl.r3, 1);
        const bool lo = (lane == 0);
        slp.r0 = lo ? 0.0f : b0;
        slp.r1 = lo ? rlane(sl.r0, 63) : b1;
        slp.r2 = lo ? rlane(sl.r1, 63) : b2;
        slp.r3 = lo ? rlane(sl.r2, 63) : b3;
    }
    Dist e, g;                                   // e[j] = v[j]+sl[j]-slp[j]; g[j] = v[j]-lam-slp[j]
    {
        float t0 = v.r0 - slp.r0, t1 = v.r1 - slp.r1, t2 = v.r2 - slp.r2, t3 = v.r3 - slp.r3;
        e.r0 = t0 + sl.r0;  e.r1 = t1 + sl.r1;  e.r2 = t2 + sl.r2;  e.r3 = t3 + sl.r3;
        g.r0 = t0 - lam;    g.r1 = t1 - lam;    g.r2 = t2 - lam;    g.r3 = t3 - lam;
    }
    const unsigned long long S0 = __ballot(d.r0 < 0.0f);
    const unsigned long long S1 = __ballot(d.r1 < 0.0f);
    const unsigned long long S2 = __ballot(d.r2 < 0.0f);
    const unsigned long long S3 = __ballot(d.r3 < 0.0f);
    const unsigned long long B20 = __ballot(fabsf(d.r0) > TWOLAM);
    const unsigned long long B21 = __ballot(fabsf(d.r1) > TWOLAM);
    const unsigned long long B22 = __ballot(fabsf(d.r2) > TWOLAM);
    const unsigned long long B23 = __ballot(fabsf(d.r3) > TWOLAM);
    const unsigned long long B40 = __ballot(fabsf(d.r0) > FOURLAM);
    const unsigned long long B41 = __ballot(fabsf(d.r1) > FOURLAM);
    const unsigned long long B42 = __ballot(fabsf(d.r2) > FOURLAM);
    const unsigned long long B43 = __ballot(fabsf(d.r3) > FOURLAM);
    // Sprev shifts S by one element across contiguous words
    const unsigned long long Sp0 = (S0 << 1);
    const unsigned long long Sp1 = (S1 << 1) | (S0 >> 63);
    const unsigned long long Sp2 = (S2 << 1) | (S1 >> 63);
    const unsigned long long Sp3 = (S3 << 1) | (S2 >> 63);
    // run-continuation: F = B4 | (B2 & same-sign-as-prev); NF = ~F (element 255 never forced)
    const unsigned long long NF0 = ~(B40 | (B20 & ~(S0 ^ Sp0)));
    const unsigned long long NF1 = ~(B41 | (B21 & ~(S1 ^ Sp1)));
    const unsigned long long NF2 = ~(B42 | (B22 & ~(S2 ^ Sp2)));
    const unsigned long long NF3 = ~((B43 | (B23 & ~(S3 ^ Sp3))) & 0x7FFFFFFFFFFFFFFFull);
    // post-jump trigger masks by ENTRY direction (threshold: same-dir 2lam, opposite 4lam)
    const unsigned long long FNn0 = (S0 & B20) | (~S0 & B40);
    const unsigned long long FNn1 = (S1 & B21) | (~S1 & B41);
    const unsigned long long FNn2 = (S2 & B22) | (~S2 & B42);
    const unsigned long long FNn3 = (S3 & B23) | (~S3 & B43);
    const unsigned long long FNp0 = (~S0 & B20) | (S0 & B40);
    const unsigned long long FNp1 = (~S1 & B21) | (S1 & B41);
    const unsigned long long FNp2 = (~S2 & B22) | (S2 & B42);
    const unsigned long long FNp3 = (~S3 & B23) | (S3 & B43);
    const int initFF = (int)(B40 & 1ull);        // conservative (|d0|>4lam => forced first jump)

    // first non-forced element >= jmin (fast path: same word)
    auto firstnf = [&](int jmin) -> int {
        const int w = jmin >> 6;
        unsigned long long m = sel4(NF0, NF1, NF2, NF3, w) >> (jmin & 63);
        if (m) return jmin + (int)__builtin_ctzll(m);
        unsigned long long m1 = (w < 1) ? NF1 : 0ull;
        unsigned long long m2 = (w < 2) ? NF2 : 0ull;
        if (m1) return 64 + (int)__builtin_ctzll(m1);
        if (m2) return 128 + (int)__builtin_ctzll(m2);
        return 192 + (int)__builtin_ctzll(NF3);  // NF3 bit63 always set -> reachable & nonzero
    };

    auto trigbit = [&](int kk, int neg) -> int {
        const int w = kk >> 6;
        const unsigned long long m = neg ? sel4(FNn0, FNn1, FNn2, FNn3, w)
                                         : sel4(FNp0, FNp1, FNp2, FNp3, w);
        return (int)((m >> (kk & 63)) & 1ull);
    };

    // ---- serial state ----
    int k = 0, k0 = 0, km = 0, kp = 0;
    float umin = lam, umax = mlam;
    const float v0 = rlane(v.r0, 0);
    float vmin = v0 - lam, vmax = v0 + lam;
    float flen = 1.0f;                  // = k - k0 + 1
    float rnext = 0.5f;                 // invariant: rnext == rcp(flen + 1)
    float vn1 = rlane(vnx.r0, 0);       // v[k+1]
    int guard = 0;

    // pre: standard-fresh at k (=k0=km=kp), next jump forced, k <= N-2.
    // EXIT direction = sign(d[k]) is looked up here (NOT the entry direction).
    auto fastfwd = [&]() {
        const int K1 = firstnf(k + 1);                        // first non-forced j > k (<= 255)
        const int sneg = (int)((sel4(S0, S1, S2, S3, k >> 6) >> (k & 63)) & 1ull); // sign(d[k])
        flushseg(o, k, k, sneg ? vmin : vmax, lane);          // first run element
        if (K1 > k + 1) {                                     // (k, K1-1]: closed-form e[j]
            const int lo = k + 1;
            const unsigned len = (unsigned)(K1 - 1 - lo);
            const int base = lane - lo;
            o.r0 = ((unsigned)(base      ) <= len) ? e.r0 : o.r0;
            o.r1 = ((unsigned)(base + 64 ) <= len) ? e.r1 : o.r1;
            o.r2 = ((unsigned)(base + 128) <= len) ? e.r2 : o.r2;
            o.r3 = ((unsigned)(base + 192) <= len) ? e.r3 : o.r3;
        }
        k = K1; k0 = K1; km = K1; kp = K1;                    // fresh at K1, entry sign = S[K1-1]
        vmin = dfetch(g, K1);                                 // = v[K1] - lam - sl[K1-1]
        vmax = vmin + twolam;
        umin = lam; umax = mlam;
        flen = 1.0f; rnext = 0.5f;
        vn1 = dfetch(vnx, K1);                                // shares lane/sel calc with g fetch
    };

    auto do_step = [&]() {
        const float un = umin + vn1 - vmin;
        const float ux = umax + vn1 - vmax;
        const bool neg = un < mlam;
        const bool pos = ux > lam;
        // speculative FF-trigger bits for the fresh landing spot k+1 (off-chain SALU)
        const int wn = (k + 1) >> 6, bn = (k + 1) & 63;
        const int tn = (int)((sel4(FNn0, FNn1, FNn2, FNn3, wn) >> bn) & 1ull);
        const int tp = (int)((sel4(FNp0, FNp1, FNp2, FNp3, wn) >> bn) & 1ull);
        if (__builtin_expect((int)(neg | pos), 1)) {          // JUMP
            const float fval = neg ? vmin : vmax;
            const int   fhi  = neg ? km : kp;
            flushseg(o, k0, fhi, fval, lane);
            const int k0n = fhi + 1;
            float vstar;
            int trig;
            if (__builtin_expect((int)(k0n <= k), 0)) {       // rewind (rare)
                vstar = dfetch(v, k0n);
                trig = trigbit(k0n, (int)neg);
            } else {                                          // fresh: renames + precomputed trig
                vstar = vn1;
                trig = neg ? tn : tp;
            }
            k = k0n; k0 = k0n; km = k0n; kp = k0n;
            vmin = neg ? vstar : vstar - twolam;
            vmax = vmin + twolam;
            umin = lam; umax = mlam;
            flen = 1.0f; rnext = 0.5f;
            if (k < N - 1 && trig) {
                fastfwd();                                    // run of guaranteed jumps
            } else {
                vn1 = dfetch(vnx, k);                         // = v[k+1] (total, clamp-free)
            }
        } else {                                              // no jump (predicated)
            k++;
            const float r = rnext;                            // = rcp(k - k0 + 1), precomputed
            flen += 1.0f;
            const bool cmin = (un >= lam);
            const bool cmax = (ux <= mlam);
            vmin = cmin ? fmaf(un - lam, r, vmin) : vmin;
            km   = cmin ? k : km;
            umin = cmin ? lam : un;
            vmax = cmax ? fmaf(ux + lam, r, vmax) : vmax;
            kp   = cmax ? k : kp;
            umax = cmax ? mlam : ux;
            vn1 = dfetch(vnx, k);                             // = v[k+1] (total, clamp-free)
            rnext = __builtin_amdgcn_rcpf(flen + 1.0f);       // off-chain for next step
        }
    };

    if (initFF) fastfwd();

    for (;;) {
        while (k < N - 1) {
            if (++guard > 2000) return; // provably terminates; belt+suspenders
            do_step();
            if (k >= N - 1) break;
            do_step();
        }
        // boundary resolution at k == N-1 (verbatim semantics from verified R2/R6)
        for (;;) {
            if (++guard > 4000) return;
            if (umin < 0.0f) {
                flushseg(o, k0, km, vmin, lane);
                k0 = km + 1;
                if (k0 > N - 1) return;
                km = k = k0;
                vmin = dfetch(v, k0);
                umin = lam;
                umax = vmin + lam - vmax;
                flen = 1.0f;
            } else if (umax > 0.0f) {
                flushseg(o, k0, kp, vmax, lane);
                k0 = kp + 1;
                if (k0 > N - 1) return;
                kp = k = k0;
                vmax = dfetch(v, k0);
                umax = mlam;
                umin = vmax - lam - vmin;
                flen = 1.0f;
            } else {
                vmin += umin / flen;
                flushseg(o, k0, k, vmin, lane);
                return;
            }
            if (k != N - 1) break;
        }
        rnext = 0.5f;                                         // flen == 1 here
        vn1 = dfetch(vnx, k);                                 // = v[k+1]
    }
}

// Packed-slot grid barrier. Each block owns one 128 B-strided uint64 slot:
// low 32 = seq (monotonic), high 32 = the block's latest row-phase max (uint
// bits of a float >= 0). Spread slots -> 64 distinct L3 lines: stores don't
// serialize, the 64-lane poll fans out in parallel. A barrier-2 poll may
// observe seq+1 (laggard) — that store carries the SAME iteration's acc, so
// the decision reduce is exact. seq+2 is impossible while any block polls.
__device__ __forceinline__ void gridbar1(unsigned long long* slots, unsigned seq,
                                         unsigned accfill, int t) {
    __syncthreads();
    __builtin_amdgcn_fence(__ATOMIC_RELEASE, "agent");        // L2 writeback only
    if (t == 0)
        __hip_atomic_store(&slots[blockIdx.x * SLOTSTRIDE],
                           ((unsigned long long)accfill << 32) | (unsigned long long)seq,
                           __ATOMIC_RELAXED, __HIP_MEMORY_SCOPE_AGENT);
    if (t < 64) {
        for (;;) {
            unsigned long long f = __hip_atomic_load(&slots[t * SLOTSTRIDE],
                                                     __ATOMIC_RELAXED, __HIP_MEMORY_SCOPE_AGENT);
            if (__all((int)((unsigned)f >= seq))) break;
        }
    }
    __builtin_amdgcn_fence(__ATOMIC_ACQUIRE, "agent");        // L2 invalidate only
    __syncthreads();
}

// barrier 2: payload-carrying; computes the grid-wide convergence decision from
// the poll's final values (free — no separate bm round trip).
__device__ __forceinline__ void gridbar2(unsigned long long* slots, unsigned seq,
                                         unsigned acc, int t, int* s_dec) {
    __syncthreads();
    __builtin_amdgcn_fence(__ATOMIC_RELEASE, "agent");
    if (t == 0)
        __hip_atomic_store(&slots[blockIdx.x * SLOTSTRIDE],
                           ((unsigned long long)acc << 32) | (unsigned long long)seq,
                           __ATOMIC_RELAXED, __HIP_MEMORY_SCOPE_AGENT);
    if (t < 64) {
        unsigned long long f;
        for (;;) {
            f = __hip_atomic_load(&slots[t * SLOTSTRIDE],
                                  __ATOMIC_RELAXED, __HIP_MEMORY_SCOPE_AGENT);
            if (__all((int)((unsigned)f >= seq))) break;
        }
        unsigned a = (unsigned)(f >> 32);
        #pragma unroll
        for (int off = 32; off > 0; off >>= 1) {
            unsigned aa = __shfl_xor(a, off);
            a = (aa > a) ? aa : a;                            // acc>=0: uint order == float order
        }
        if (t == 0) *s_dec = (__uint_as_float(a) < TOL) ? 1 : 0;
    }
    __builtin_amdgcn_fence(__ATOMIC_ACQUIRE, "agent");
    __syncthreads();
}

// Douglas-Rachford TV2D. Wave w of block b owns column (4b+w) in phase 1 and row
// (4b+w) in phase 2. Coalesced float4 + LDS-transpose I/O (R17); packed-slot
// barriers with in-poll convergence decision; final-iteration barrier skipped.
__global__ __launch_bounds__(NT) void tv2d_coop(const float* __restrict__ X,
                                                float* __restrict__ xw,     // = d_out
                                                float* __restrict__ y,      // holds yT
                                                unsigned long long* __restrict__ slots)
{
    const int t = threadIdx.x;
    const int lane = t & 63;
    const int wave = t >> 6;
    const int line = blockIdx.x * NLINE + wave;
    const int col4 = 4 * blockIdx.x;             // block's 4-column / 4-row group
    __shared__ float tile[N * 5];                // transpose tile, stride-5 padded
    __shared__ unsigned s_acc;
    __shared__ int s_dec;
    if (t == 0) s_acc = 0u;

    Dist p = {0.f, 0.f, 0.f, 0.f};
    Dist q = {0.f, 0.f, 0.f, 0.f};
    unsigned accprev = 0u;                       // block's acc from previous iteration

    for (int it = 0; it < MAXIT; ++it) {
        // ---- column phase: y = prox(x + p) on column `line`; p = v - y ----
        const float* xs = (it == 0) ? X : xw;
        const float4 xc = *(const float4*)(xs + t * N + col4);  // coalesced row-chunk
        tile[t * 5 + 0] = xc.x;                 // transpose deposit: tile[row][c]
        tile[t * 5 + 1] = xc.y;
        tile[t * 5 + 2] = xc.z;
        tile[t * 5 + 3] = xc.w;
        __syncthreads();
        Dist v, o;
        v.r0 = tile[(lane      ) * 5 + wave] + p.r0;   // column `line` from LDS
        v.r1 = tile[(lane + 64 ) * 5 + wave] + p.r1;
        v.r2 = tile[(lane + 128) * 5 + wave] + p.r2;
        v.r3 = tile[(lane + 192) * 5 + wave] + p.r3;
        tv1d_scan(v, o, lane);
        p.r0 = v.r0 - o.r0;  p.r1 = v.r1 - o.r1;
        p.r2 = v.r2 - o.r2;  p.r3 = v.r3 - o.r3;
        float* yt = y + line * N;               // y stored TRANSPOSED -> coalesced
        yt[lane      ] = o.r0;
        yt[lane + 64 ] = o.r1;
        yt[lane + 128] = o.r2;
        yt[lane + 192] = o.r3;
        gridbar1(slots, 2u * (unsigned)it + 1u, accprev, t);

        // ---- row phase: x2 = prox(y + q) on row `line`; q = v - x2; acc = max|y-x2| ----
        const float4 yc = *(const float4*)(y + t * N + col4);
        tile[t * 5 + 0] = yc.x;                 // tile[j][c] = y[col4+c][j]
        tile[t * 5 + 1] = yc.y;
        tile[t * 5 + 2] = yc.z;
        tile[t * 5 + 3] = yc.w;
        __syncthreads();
        float y0 = tile[(lane      ) * 5 + wave];      // row `line` elements
        float y1 = tile[(lane + 64 ) * 5 + wave];
        float y2 = tile[(lane + 128) * 5 + wave];
        float y3 = tile[(lane + 192) * 5 + wave];
        Dist w, o2;
        w.r0 = y0 + q.r0;
        w.r1 = y1 + q.r1;
        w.r2 = y2 + q.r2;
        w.r3 = y3 + q.r3;
        tv1d_scan(w, o2, lane);
        float d0 = y0 - o2.r0;    // y - x2
        float d1 = y1 - o2.r1;
        float d2 = y2 - o2.r2;
        float d3 = y3 - o2.r3;
        q.r0 = w.r0 - o2.r0;  q.r1 = w.r1 - o2.r1;
        q.r2 = w.r2 - o2.r2;  q.r3 = w.r3 - o2.r3;
        float* xr = xw + line * N;              // row-major, coalesced
        xr[lane      ] = o2.r0;
        xr[lane + 64 ] = o2.r1;
        xr[lane + 128] = o2.r2;
        xr[lane + 192] = o2.r3;

        float am = fmaxf(fmaxf(fabsf(d0), fabsf(d1)), fmaxf(fabsf(d2), fabsf(d3)));
        #pragma unroll
        for (int off = 32; off > 0; off >>= 1)
            am = fmaxf(am, __shfl_xor(am, off));
        if (lane == 0) atomicMax(&s_acc, __float_as_uint(am));   // LDS atomic, 4/block
        __syncthreads();                                          // s_acc complete
        const unsigned ba = s_acc;                                // everyone reads before reset

        if (it == MAXIT - 1) break;             // nothing after the last row phase is read

        // ---- barrier 2: packed {acc, seq}; decision computed in-poll ----
        gridbar2(slots, 2u * (unsigned)it + 2u, ba, t, &s_dec);   // leading syncthreads orders ba reads
        if (t == 0) s_acc = 0u;                 // safe: next atomicMax is after gridbar1 of it+1
        if (s_dec) break;                       // xw holds x2 of `it` (reference output)
        accprev = ba;
    }
}

extern "C" void kernel_launch(void* const* d_in, const int* in_sizes, int n_in,
                              void* d_out, int out_size, void* d_ws, size_t ws_size,
                              hipStream_t stream) {
    const float* X = (const float*)d_in[0];
    float* xw = (float*)d_out;
    float* y = (float*)d_ws;
    unsigned long long* slots = (unsigned long long*)((char*)d_ws + (size_t)N * N * sizeof(float));
    // zero the slot array (64 slots x 128 B) before the kernel (capture-legal)
    (void)hipMemsetAsync((void*)slots, 0, NB * SLOTSTRIDE * sizeof(unsigned long long), stream);
    void* args[] = { (void*)&X, (void*)&xw, (void*)&y, (void*)&slots };
    (void)hipLaunchCooperativeKernel((void*)tv2d_coop, dim3(NB), dim3(NT), args, 0, stream);
}

// Round 19
// 293.857 us; speedup vs baseline: 1.1640x; 1.0368x over previous
//
#include <hip/hip_runtime.h>

#define N 256
#define NLINE 4               // lines (waves) per block
#define NB (N / NLINE)        // 64 blocks
#define NT (NLINE * 64)       // 256 threads
#define LAM 0.05f             // step = ALPHA/2
#define TWOLAM (2.0f * LAM)
#define FOURLAM (4.0f * LAM)
#define MAXIT 35
#define TOL 0.01f
#define SLOTSTRIDE 16         // uint64 elements -> 128 B per block slot (own L3 line)

// broadcast-read one lane's register (lane index is wave-uniform -> v_readlane)
__device__ __forceinline__ float rlane(float v, int lane) {
    return __int_as_float(__builtin_amdgcn_readlane(__float_as_int(v), lane));
}

// agent-scope (L2-bypassing) data access for cross-block-communicated arrays.
// No dirty L2 lines, no stale L2 copies -> grid barrier needs NO cache wb/inv.
__device__ __forceinline__ float gload(const float* p) {
    return __hip_atomic_load((const float*)p, __ATOMIC_RELAXED, __HIP_MEMORY_SCOPE_AGENT);
}
__device__ __forceinline__ void gstore(float* p, float v) {
    __hip_atomic_store(p, v, __ATOMIC_RELAXED, __HIP_MEMORY_SCOPE_AGENT);
}

// 256-float line distributed over the wave: element k lives in lane (k&63), reg (k>>6)
// -> ballot words are CONTIGUOUS 64-element spans (word w = elements 64w..64w+63)
struct Dist { float r0, r1, r2, r3; };

// branchless fetch: 4 independent readlanes + 2 uniform selects
__device__ __forceinline__ float dfetch(const Dist& d, int k) {
    const int lane = k & 63;
    const int sel = k >> 6;
    float a = rlane(d.r0, lane);
    float b = rlane(d.r1, lane);
    float c = rlane(d.r2, lane);
    float e = rlane(d.r3, lane);
    float ab = (sel & 1) ? b : a;
    float ce = (sel & 1) ? e : c;
    return (sel & 2) ? ce : ab;
}

// O(1) segment flush: o[j] = val for j in [lo, hi]; element j of reg r = 64r + lane
__device__ __forceinline__ void flushseg(Dist& o, int lo, int hi, float val, int lane) {
    const unsigned len = (unsigned)(hi - lo);
    const int base = lane - lo;
    o.r0 = ((unsigned)(base      ) <= len) ? val : o.r0;
    o.r1 = ((unsigned)(base + 64 ) <= len) ? val : o.r1;
    o.r2 = ((unsigned)(base + 128) <= len) ? val : o.r2;
    o.r3 = ((unsigned)(base + 192) <= len) ? val : o.r3;
}

// scalar 4-way select of a 64-bit mask (s_cselect_b64)
__device__ __forceinline__ unsigned long long sel4(unsigned long long a, unsigned long long b,
                                                   unsigned long long c, unsigned long long d, int r) {
    unsigned long long ab = (r & 1) ? b : a;
    unsigned long long cd = (r & 1) ? d : c;
    return (r & 2) ? cd : ab;
}

// Condat's exact 1D TV prox (verified R14 version, unchanged this round).
__device__ void tv1d_scan(const Dist& v, Dist& o, const int lane)
{
    const float lam = LAM, mlam = -LAM, twolam = TWOLAM;

    // ---- per-scan precompute (vectorized) ----
    Dist vnx;                                    // vnx[j] = v[j+1] for j<255; vnx[255] = v[255]
    {
        float a0 = __shfl_down(v.r0, 1), a1 = __shfl_down(v.r1, 1);
        float a2 = __shfl_down(v.r2, 1), a3 = __shfl_down(v.r3, 1);
        const bool hi = (lane == 63);
        vnx.r0 = hi ? rlane(v.r1, 0) : a0;
        vnx.r1 = hi ? rlane(v.r2, 0) : a1;
        vnx.r2 = hi ? rlane(v.r3, 0) : a2;
        vnx.r3 = hi ? v.r3 : a3;                 // element 255 -> v[255] (safe total fetch)
    }
    Dist d;
    d.r0 = vnx.r0 - v.r0;  d.r1 = vnx.r1 - v.r1;
    d.r2 = vnx.r2 - v.r2;  d.r3 = vnx.r3 - v.r3;
    const unsigned lambits = __float_as_uint(lam);
    Dist sl;                                     // sl[j] = sign(d[j]) * lam
    sl.r0 = __uint_as_float((__float_as_uint(d.r0) & 0x80000000u) | lambits);
    sl.r1 = __uint_as_float((__float_as_uint(d.r1) & 0x80000000u) | lambits);
    sl.r2 = __uint_as_float((__float_as_uint(d.r2) & 0x80000000u) | lambits);
    sl.r3 = __uint_as_float((__float_as_uint(d.r3) & 0x80000000u) | lambits);
    Dist slp;                                    // slp[j] = sl[j-1], slp[0] = 0
    {
        float b0 = __shfl_up(sl.r0, 1), b1 = __shfl_up(sl.r1, 1);
        float b2 = __shfl_up(sl.r2, 1), b3 = __shfl_up(sl.r3, 1);
        const bool lo = (lane == 0);
        slp.r0 = lo ? 0.0f : b0;
        slp.r1 = lo ? rlane(sl.r0, 63) : b1;
        slp.r2 = lo ? rlane(sl.r1, 63) : b2;
        slp.r3 = lo ? rlane(sl.r2, 63) : b3;
    }
    Dist e, g;                                   // e[j] = v[j]+sl[j]-slp[j]; g[j] = v[j]-lam-slp[j]
    {
        float t0 = v.r0 - slp.r0, t1 = v.r1 - slp.r1, t2 = v.r2 - slp.r2, t3 = v.r3 - slp.r3;
        e.r0 = t0 + sl.r0;  e.r1 = t1 + sl.r1;  e.r2 = t2 + sl.r2;  e.r3 = t3 + sl.r3;
        g.r0 = t0 - lam;    g.r1 = t1 - lam;    g.r2 = t2 - lam;    g.r3 = t3 - lam;
    }
    const unsigned long long S0 = __ballot(d.r0 < 0.0f);
    const unsigned long long S1 = __ballot(d.r1 < 0.0f);
    const unsigned long long S2 = __ballot(d.r2 < 0.0f);
    const unsigned long long S3 = __ballot(d.r3 < 0.0f);
    const unsigned long long B20 = __ballot(fabsf(d.r0) > TWOLAM);
    const unsigned long long B21 = __ballot(fabsf(d.r1) > TWOLAM);
    const unsigned long long B22 = __ballot(fabsf(d.r2) > TWOLAM);
    const unsigned long long B23 = __ballot(fabsf(d.r3) > TWOLAM);
    const unsigned long long B40 = __ballot(fabsf(d.r0) > FOURLAM);
    const unsigned long long B41 = __ballot(fabsf(d.r1) > FOURLAM);
    const unsigned long long B42 = __ballot(fabsf(d.r2) > FOURLAM);
    const unsigned long long B43 = __ballot(fabsf(d.r3) > FOURLAM);
    // Sprev shifts S by one element across contiguous words
    const unsigned long long Sp0 = (S0 << 1);
    const unsigned long long Sp1 = (S1 << 1) | (S0 >> 63);
    const unsigned long long Sp2 = (S2 << 1) | (S1 >> 63);
    const unsigned long long Sp3 = (S3 << 1) | (S2 >> 63);
    // run-continuation: F = B4 | (B2 & same-sign-as-prev); NF = ~F (element 255 never forced)
    const unsigned long long NF0 = ~(B40 | (B20 & ~(S0 ^ Sp0)));
    const unsigned long long NF1 = ~(B41 | (B21 & ~(S1 ^ Sp1)));
    const unsigned long long NF2 = ~(B42 | (B22 & ~(S2 ^ Sp2)));
    const unsigned long long NF3 = ~((B43 | (B23 & ~(S3 ^ Sp3))) & 0x7FFFFFFFFFFFFFFFull);
    // post-jump trigger masks by ENTRY direction (threshold: same-dir 2lam, opposite 4lam)
    const unsigned long long FNn0 = (S0 & B20) | (~S0 & B40);
    const unsigned long long FNn1 = (S1 & B21) | (~S1 & B41);
    const unsigned long long FNn2 = (S2 & B22) | (~S2 & B42);
    const unsigned long long FNn3 = (S3 & B23) | (~S3 & B43);
    const unsigned long long FNp0 = (~S0 & B20) | (S0 & B40);
    const unsigned long long FNp1 = (~S1 & B21) | (S1 & B41);
    const unsigned long long FNp2 = (~S2 & B22) | (S2 & B42);
    const unsigned long long FNp3 = (~S3 & B23) | (S3 & B43);
    const int initFF = (int)(B40 & 1ull);        // conservative (|d0|>4lam => forced first jump)

    // first non-forced element >= jmin (fast path: same word)
    auto firstnf = [&](int jmin) -> int {
        const int w = jmin >> 6;
        unsigned long long m = sel4(NF0, NF1, NF2, NF3, w) >> (jmin & 63);
        if (m) return jmin + (int)__builtin_ctzll(m);
        unsigned long long m1 = (w < 1) ? NF1 : 0ull;
        unsigned long long m2 = (w < 2) ? NF2 : 0ull;
        if (m1) return 64 + (int)__builtin_ctzll(m1);
        if (m2) return 128 + (int)__builtin_ctzll(m2);
        return 192 + (int)__builtin_ctzll(NF3);  // NF3 bit63 always set -> reachable & nonzero
    };

    auto trigbit = [&](int kk, int neg) -> int {
        const int w = kk >> 6;
        const unsigned long long m = neg ? sel4(FNn0, FNn1, FNn2, FNn3, w)
                                         : sel4(FNp0, FNp1, FNp2, FNp3, w);
        return (int)((m >> (kk & 63)) & 1ull);
    };

    // ---- serial state ----
    int k = 0, k0 = 0, km = 0, kp = 0;
    float umin = lam, umax = mlam;
    const float v0 = rlane(v.r0, 0);
    float vmin = v0 - lam, vmax = v0 + lam;
    float flen = 1.0f;                  // = k - k0 + 1
    float rnext = 0.5f;                 // invariant: rnext == rcp(flen + 1)
    float vn1 = rlane(vnx.r0, 0);       // v[k+1]
    int guard = 0;

    // pre: standard-fresh at k (=k0=km=kp), next jump forced, k <= N-2.
    // EXIT direction = sign(d[k]) is looked up here (NOT the entry direction).
    auto fastfwd = [&]() {
        const int K1 = firstnf(k + 1);                        // first non-forced j > k (<= 255)
        const int sneg = (int)((sel4(S0, S1, S2, S3, k >> 6) >> (k & 63)) & 1ull); // sign(d[k])
        flushseg(o, k, k, sneg ? vmin : vmax, lane);          // first run element
        if (K1 > k + 1) {                                     // (k, K1-1]: closed-form e[j]
            const int lo = k + 1;
            const unsigned len = (unsigned)(K1 - 1 - lo);
            const int base = lane - lo;
            o.r0 = ((unsigned)(base      ) <= len) ? e.r0 : o.r0;
            o.r1 = ((unsigned)(base + 64 ) <= len) ? e.r1 : o.r1;
            o.r2 = ((unsigned)(base + 128) <= len) ? e.r2 : o.r2;
            o.r3 = ((unsigned)(base + 192) <= len) ? e.r3 : o.r3;
        }
        k = K1; k0 = K1; km = K1; kp = K1;                    // fresh at K1, entry sign = S[K1-1]
        vmin = dfetch(g, K1);                                 // = v[K1] - lam - sl[K1-1]
        vmax = vmin + twolam;
        umin = lam; umax = mlam;
        flen = 1.0f; rnext = 0.5f;
        vn1 = dfetch(vnx, K1);                                // shares lane/sel calc with g fetch
    };

    auto do_step = [&]() {
        const float un = umin + vn1 - vmin;
        const float ux = umax + vn1 - vmax;
        const bool neg = un < mlam;
        const bool pos = ux > lam;
        // speculative FF-trigger bits for the fresh landing spot k+1 (off-chain SALU)
        const int wn = (k + 1) >> 6, bn = (k + 1) & 63;
        const int tn = (int)((sel4(FNn0, FNn1, FNn2, FNn3, wn) >> bn) & 1ull);
        const int tp = (int)((sel4(FNp0, FNp1, FNp2, FNp3, wn) >> bn) & 1ull);
        if (__builtin_expect((int)(neg | pos), 1)) {          // JUMP
            const float fval = neg ? vmin : vmax;
            const int   fhi  = neg ? km : kp;
            flushseg(o, k0, fhi, fval, lane);
            const int k0n = fhi + 1;
            float vstar;
            int trig;
            if (__builtin_expect((int)(k0n <= k), 0)) {       // rewind (rare)
                vstar = dfetch(v, k0n);
                trig = trigbit(k0n, (int)neg);
            } else {                                          // fresh: renames + precomputed trig
                vstar = vn1;
                trig = neg ? tn : tp;
            }
            k = k0n; k0 = k0n; km = k0n; kp = k0n;
            vmin = neg ? vstar : vstar - twolam;
            vmax = vmin + twolam;
            umin = lam; umax = mlam;
            flen = 1.0f; rnext = 0.5f;
            if (k < N - 1 && trig) {
                fastfwd();                                    // run of guaranteed jumps
            } else {
                vn1 = dfetch(vnx, k);                         // = v[k+1] (total, clamp-free)
            }
        } else {                                              // no jump (predicated)
            k++;
            const float r = rnext;                            // = rcp(k - k0 + 1), precomputed
            flen += 1.0f;
            const bool cmin = (un >= lam);
            const bool cmax = (ux <= mlam);
            vmin = cmin ? fmaf(un - lam, r, vmin) : vmin;
            km   = cmin ? k : km;
            umin = cmin ? lam : un;
            vmax = cmax ? fmaf(ux + lam, r, vmax) : vmax;
            kp   = cmax ? k : kp;
            umax = cmax ? mlam : ux;
            vn1 = dfetch(vnx, k);                             // = v[k+1] (total, clamp-free)
            rnext = __builtin_amdgcn_rcpf(flen + 1.0f);       // off-chain for next step
        }
    };

    if (initFF) fastfwd();

    for (;;) {
        while (k < N - 1) {
            if (++guard > 2000) return; // provably terminates; belt+suspenders
            do_step();
            if (k >= N - 1) break;
            do_step();
        }
        // boundary resolution at k == N-1 (verbatim semantics from verified R2/R6)
        for (;;) {
            if (++guard > 4000) return;
            if (umin < 0.0f) {
                flushseg(o, k0, km, vmin, lane);
                k0 = km + 1;
                if (k0 > N - 1) return;
                km = k = k0;
                vmin = dfetch(v, k0);
                umin = lam;
                umax = vmin + lam - vmax;
                flen = 1.0f;
            } else if (umax > 0.0f) {
                flushseg(o, k0, kp, vmax, lane);
                k0 = kp + 1;
                if (k0 > N - 1) return;
                kp = k = k0;
                vmax = dfetch(v, k0);
                umax = mlam;
                umin = vmax - lam - vmin;
                flen = 1.0f;
            } else {
                vmin += umin / flen;
                flushseg(o, k0, k, vmin, lane);
                return;
            }
            if (k != N - 1) break;
        }
        rnext = 0.5f;                                         // flen == 1 here
        vn1 = dfetch(vnx, k);                                 // = v[k+1]
    }
}

// Packed-slot grid barrier over L2-bypassing data: all communicated arrays are
// agent-scope (sc1), so NO cache wb/inv is needed — only ordering. s_waitcnt(0)
// drains the data stores before the flag store, and drains the poll before the
// next phase's loads. Slots are 128 B-strided (own L3 lines).
__device__ __forceinline__ void gridbar1(unsigned long long* slots, unsigned seq,
                                         unsigned accfill, int t) {
    __syncthreads();
    __builtin_amdgcn_s_waitcnt(0);                            // vmcnt(0) lgkmcnt(0): stores drained
    if (t == 0)
        __hip_atomic_store(&slots[blockIdx.x * SLOTSTRIDE],
                           ((unsigned long long)accfill << 32) | (unsigned long long)seq,
                           __ATOMIC_RELAXED, __HIP_MEMORY_SCOPE_AGENT);
    if (t < 64) {
        for (;;) {
            unsigned long long f = __hip_atomic_load(&slots[t * SLOTSTRIDE],
                                                     __ATOMIC_RELAXED, __HIP_MEMORY_SCOPE_AGENT);
            if (__all((int)((unsigned)f >= seq))) break;
        }
    }
    __builtin_amdgcn_s_waitcnt(0);
    __syncthreads();
}

// barrier 2: payload-carrying; computes the grid-wide convergence decision from
// the poll's final values (free — no separate bm round trip).
__device__ __forceinline__ void gridbar2(unsigned long long* slots, unsigned seq,
                                         unsigned acc, int t, int* s_dec) {
    __syncthreads();
    __builtin_amdgcn_s_waitcnt(0);
    if (t == 0)
        __hip_atomic_store(&slots[blockIdx.x * SLOTSTRIDE],
                           ((unsigned long long)acc << 32) | (unsigned long long)seq,
                           __ATOMIC_RELAXED, __HIP_MEMORY_SCOPE_AGENT);
    if (t < 64) {
        unsigned long long f;
        for (;;) {
            f = __hip_atomic_load(&slots[t * SLOTSTRIDE],
                                  __ATOMIC_RELAXED, __HIP_MEMORY_SCOPE_AGENT);
            if (__all((int)((unsigned)f >= seq))) break;
        }
        unsigned a = (unsigned)(f >> 32);
        #pragma unroll
        for (int off = 32; off > 0; off >>= 1) {
            unsigned aa = __shfl_xor(a, off);
            a = (aa > a) ? aa : a;                            // acc>=0: uint order == float order
        }
        if (t == 0) *s_dec = (__uint_as_float(a) < TOL) ? 1 : 0;
    }
    __builtin_amdgcn_s_waitcnt(0);
    __syncthreads();
}

// Douglas-Rachford TV2D. Wave w of block b owns column (4b+w) in phase 1 and row
// (4b+w) in phase 2. Coalesced + LDS-transpose I/O; all y/xw traffic is
// agent-scope (L2-bypassing) so barriers need no cache maintenance.
__global__ __launch_bounds__(NT) void tv2d_coop(const float* __restrict__ X,
                                                float* __restrict__ xw,     // = d_out
                                                float* __restrict__ y,      // holds yT
                                                unsigned long long* __restrict__ slots)
{
    const int t = threadIdx.x;
    const int lane = t & 63;
    const int wave = t >> 6;
    const int line = blockIdx.x * NLINE + wave;
    const int col4 = 4 * blockIdx.x;             // block's 4-column / 4-row group
    __shared__ float tile[N * 5];                // transpose tile, stride-5 padded
    __shared__ unsigned s_acc;
    __shared__ int s_dec;
    if (t == 0) s_acc = 0u;

    Dist p = {0.f, 0.f, 0.f, 0.f};
    Dist q = {0.f, 0.f, 0.f, 0.f};
    unsigned accprev = 0u;                       // block's acc from previous iteration

    for (int it = 0; it < MAXIT; ++it) {
        // ---- column phase: y = prox(x + p) on column `line`; p = v - y ----
        const float* xs = (it == 0) ? X : xw;
        const float* xp = xs + t * N + col4;
        float x0 = gload(xp + 0);               // agent loads (L2-bypass), bulk-issued
        float x1 = gload(xp + 1);
        float x2 = gload(xp + 2);
        float x3 = gload(xp + 3);
        tile[t * 5 + 0] = x0;                   // transpose deposit: tile[row][c]
        tile[t * 5 + 1] = x1;
        tile[t * 5 + 2] = x2;
        tile[t * 5 + 3] = x3;
        __syncthreads();
        Dist v, o;
        v.r0 = tile[(lane      ) * 5 + wave] + p.r0;   // column `line` from LDS
        v.r1 = tile[(lane + 64 ) * 5 + wave] + p.r1;
        v.r2 = tile[(lane + 128) * 5 + wave] + p.r2;
        v.r3 = tile[(lane + 192) * 5 + wave] + p.r3;
        tv1d_scan(v, o, lane);
        p.r0 = v.r0 - o.r0;  p.r1 = v.r1 - o.r1;
        p.r2 = v.r2 - o.r2;  p.r3 = v.r3 - o.r3;
        float* yt = y + line * N;               // y stored TRANSPOSED -> coalesced
        gstore(yt + lane,       o.r0);
        gstore(yt + lane + 64,  o.r1);
        gstore(yt + lane + 128, o.r2);
        gstore(yt + lane + 192, o.r3);
        gridbar1(slots, 2u * (unsigned)it + 1u, accprev, t);

        // ---- row phase: x2 = prox(y + q) on row `line`; q = v - x2; acc = max|y-x2| ----
        const float* yp = y + t * N + col4;
        float ya = gload(yp + 0);
        float yb = gload(yp + 1);
        float yc2 = gload(yp + 2);
        float yd = gload(yp + 3);
        tile[t * 5 + 0] = ya;                   // tile[j][c] = y[col4+c][j]
        tile[t * 5 + 1] = yb;
        tile[t * 5 + 2] = yc2;
        tile[t * 5 + 3] = yd;
        __syncthreads();
        float y0 = tile[(lane      ) * 5 + wave];      // row `line` elements
        float y1 = tile[(lane + 64 ) * 5 + wave];
        float y2 = tile[(lane + 128) * 5 + wave];
        float y3 = tile[(lane + 192) * 5 + wave];
        Dist w, o2;
        w.r0 = y0 + q.r0;
        w.r1 = y1 + q.r1;
        w.r2 = y2 + q.r2;
        w.r3 = y3 + q.r3;
        tv1d_scan(w, o2, lane);
        float d0 = y0 - o2.r0;    // y - x2
        float d1 = y1 - o2.r1;
        float d2 = y2 - o2.r2;
        float d3 = y3 - o2.r3;
        q.r0 = w.r0 - o2.r0;  q.r1 = w.r1 - o2.r1;
        q.r2 = w.r2 - o2.r2;  q.r3 = w.r3 - o2.r3;
        float* xr = xw + line * N;              // row-major, coalesced
        gstore(xr + lane,       o2.r0);
        gstore(xr + lane + 64,  o2.r1);
        gstore(xr + lane + 128, o2.r2);
        gstore(xr + lane + 192, o2.r3);

        float am = fmaxf(fmaxf(fabsf(d0), fabsf(d1)), fmaxf(fabsf(d2), fabsf(d3)));
        #pragma unroll
        for (int off = 32; off > 0; off >>= 1)
            am = fmaxf(am, __shfl_xor(am, off));
        if (lane == 0) atomicMax(&s_acc, __float_as_uint(am));   // LDS atomic, 4/block
        __syncthreads();                                          // s_acc complete
        const unsigned ba = s_acc;                                // everyone reads before reset

        if (it == MAXIT - 1) break;             // nothing after the last row phase is read

        // ---- barrier 2: packed {acc, seq}; decision computed in-poll ----
        gridbar2(slots, 2u * (unsigned)it + 2u, ba, t, &s_dec);   // leading syncthreads orders ba reads
        if (t == 0) s_acc = 0u;                 // safe: next atomicMax is after gridbar1 of it+1
        if (s_dec) break;                       // xw holds x2 of `it` (reference output)
        accprev = ba;
    }
}

extern "C" void kernel_launch(void* const* d_in, const int* in_sizes, int n_in,
                              void* d_out, int out_size, void* d_ws, size_t ws_size,
                              hipStream_t stream) {
    const float* X = (const float*)d_in[0];
    float* xw = (float*)d_out;
    float* y = (float*)d_ws;
    unsigned long long* slots = (unsigned long long*)((char*)d_ws + (size_t)N * N * sizeof(float));
    // zero the slot array (64 slots x 128 B) before the kernel (capture-legal)
    (void)hipMemsetAsync((void*)slots, 0, NB * SLOTSTRIDE * sizeof(unsigned long long), stream);
    void* args[] = { (void*)&X, (void*)&xw, (void*)&y, (void*)&slots };
    (void)hipLaunchCooperativeKernel((void*)tv2d_coop, dim3(NB), dim3(NT), args, 0, stream);
}

// Round 20
// 283.725 us; speedup vs baseline: 1.2056x; 1.0357x over previous
//
#include <hip/hip_runtime.h>

#define N 256
#define NLINE 4               // lines (waves) per block
#define NB (N / NLINE)        // 64 blocks
#define NT (NLINE * 64)       // 256 threads
#define LAM 0.05f             // step = ALPHA/2
#define TWOLAM (2.0f * LAM)
#define FOURLAM (4.0f * LAM)
#define MAXIT 35
#define TOL 0.01f
#define SLOTSTRIDE 16         // uint64 elements -> 128 B per block slot (own L3 line)

// broadcast-read one lane's register (lane index is wave-uniform -> v_readlane)
__device__ __forceinline__ float rlane(float v, int lane) {
    return __int_as_float(__builtin_amdgcn_readlane(__float_as_int(v), lane));
}

// agent-scope (L2-bypassing) scalar access for cross-block-communicated arrays.
__device__ __forceinline__ void gstore(float* p, float v) {
    __hip_atomic_store(p, v, __ATOMIC_RELAXED, __HIP_MEMORY_SCOPE_AGENT);
}
// 16-byte L2-bypassing load (sc0 sc1 = coherent scope, L3-served — never caches
// in L2, so the no-cache-maintenance barrier remains correct). Alignment: all
// call sites are (base + t*N + 4*blk)*4 B = 16 B-aligned.
__device__ __forceinline__ float4 gload4(const float* p) {
    float4 r;
    asm volatile("global_load_dwordx4 %0, %1, off sc0 sc1\n\ts_waitcnt vmcnt(0)"
                 : "=&v"(r) : "v"(p) : "memory");
    return r;
}

// 256-float line distributed over the wave: element k lives in lane (k&63), reg (k>>6)
// -> ballot words are CONTIGUOUS 64-element spans (word w = elements 64w..64w+63)
struct Dist { float r0, r1, r2, r3; };

// branchless fetch: 4 independent readlanes + 2 uniform selects
__device__ __forceinline__ float dfetch(const Dist& d, int k) {
    const int lane = k & 63;
    const int sel = k >> 6;
    float a = rlane(d.r0, lane);
    float b = rlane(d.r1, lane);
    float c = rlane(d.r2, lane);
    float e = rlane(d.r3, lane);
    float ab = (sel & 1) ? b : a;
    float ce = (sel & 1) ? e : c;
    return (sel & 2) ? ce : ab;
}

// O(1) segment flush: o[j] = val for j in [lo, hi]; element j of reg r = 64r + lane
__device__ __forceinline__ void flushseg(Dist& o, int lo, int hi, float val, int lane) {
    const unsigned len = (unsigned)(hi - lo);
    const int base = lane - lo;
    o.r0 = ((unsigned)(base      ) <= len) ? val : o.r0;
    o.r1 = ((unsigned)(base + 64 ) <= len) ? val : o.r1;
    o.r2 = ((unsigned)(base + 128) <= len) ? val : o.r2;
    o.r3 = ((unsigned)(base + 192) <= len) ? val : o.r3;
}

// scalar 4-way select of a 64-bit mask (s_cselect_b64)
__device__ __forceinline__ unsigned long long sel4(unsigned long long a, unsigned long long b,
                                                   unsigned long long c, unsigned long long d, int r) {
    unsigned long long ab = (r & 1) ? b : a;
    unsigned long long cd = (r & 1) ? d : c;
    return (r & 2) ? cd : ab;
}

// Condat's exact 1D TV prox (verified R14 version, unchanged this round).
__device__ void tv1d_scan(const Dist& v, Dist& o, const int lane)
{
    const float lam = LAM, mlam = -LAM, twolam = TWOLAM;

    // ---- per-scan precompute (vectorized) ----
    Dist vnx;                                    // vnx[j] = v[j+1] for j<255; vnx[255] = v[255]
    {
        float a0 = __shfl_down(v.r0, 1), a1 = __shfl_down(v.r1, 1);
        float a2 = __shfl_down(v.r2, 1), a3 = __shfl_down(v.r3, 1);
        const bool hi = (lane == 63);
        vnx.r0 = hi ? rlane(v.r1, 0) : a0;
        vnx.r1 = hi ? rlane(v.r2, 0) : a1;
        vnx.r2 = hi ? rlane(v.r3, 0) : a2;
        vnx.r3 = hi ? v.r3 : a3;                 // element 255 -> v[255] (safe total fetch)
    }
    Dist d;
    d.r0 = vnx.r0 - v.r0;  d.r1 = vnx.r1 - v.r1;
    d.r2 = vnx.r2 - v.r2;  d.r3 = vnx.r3 - v.r3;
    const unsigned lambits = __float_as_uint(lam);
    Dist sl;                                     // sl[j] = sign(d[j]) * lam
    sl.r0 = __uint_as_float((__float_as_uint(d.r0) & 0x80000000u) | lambits);
    sl.r1 = __uint_as_float((__float_as_uint(d.r1) & 0x80000000u) | lambits);
    sl.r2 = __uint_as_float((__float_as_uint(d.r2) & 0x80000000u) | lambits);
    sl.r3 = __uint_as_float((__float_as_uint(d.r3) & 0x80000000u) | lambits);
    Dist slp;                                    // slp[j] = sl[j-1], slp[0] = 0
    {
        float b0 = __shfl_up(sl.r0, 1), b1 = __shfl_up(sl.r1, 1);
        float b2 = __shfl_up(sl.r2, 1), b3 = __shfl_up(sl.r3, 1);
        const bool lo = (lane == 0);
        slp.r0 = lo ? 0.0f : b0;
        slp.r1 = lo ? rlane(sl.r0, 63) : b1;
        slp.r2 = lo ? rlane(sl.r1, 63) : b2;
        slp.r3 = lo ? rlane(sl.r2, 63) : b3;
    }
    Dist e, g;                                   // e[j] = v[j]+sl[j]-slp[j]; g[j] = v[j]-lam-slp[j]
    {
        float t0 = v.r0 - slp.r0, t1 = v.r1 - slp.r1, t2 = v.r2 - slp.r2, t3 = v.r3 - slp.r3;
        e.r0 = t0 + sl.r0;  e.r1 = t1 + sl.r1;  e.r2 = t2 + sl.r2;  e.r3 = t3 + sl.r3;
        g.r0 = t0 - lam;    g.r1 = t1 - lam;    g.r2 = t2 - lam;    g.r3 = t3 - lam;
    }
    const unsigned long long S0 = __ballot(d.r0 < 0.0f);
    const unsigned long long S1 = __ballot(d.r1 < 0.0f);
    const unsigned long long S2 = __ballot(d.r2 < 0.0f);
    const unsigned long long S3 = __ballot(d.r3 < 0.0f);
    const unsigned long long B20 = __ballot(fabsf(d.r0) > TWOLAM);
    const unsigned long long B21 = __ballot(fabsf(d.r1) > TWOLAM);
    const unsigned long long B22 = __ballot(fabsf(d.r2) > TWOLAM);
    const unsigned long long B23 = __ballot(fabsf(d.r3) > TWOLAM);
    const unsigned long long B40 = __ballot(fabsf(d.r0) > FOURLAM);
    const unsigned long long B41 = __ballot(fabsf(d.r1) > FOURLAM);
    const unsigned long long B42 = __ballot(fabsf(d.r2) > FOURLAM);
    const unsigned long long B43 = __ballot(fabsf(d.r3) > FOURLAM);
    // Sprev shifts S by one element across contiguous words
    const unsigned long long Sp0 = (S0 << 1);
    const unsigned long long Sp1 = (S1 << 1) | (S0 >> 63);
    const unsigned long long Sp2 = (S2 << 1) | (S1 >> 63);
    const unsigned long long Sp3 = (S3 << 1) | (S2 >> 63);
    // run-continuation: F = B4 | (B2 & same-sign-as-prev); NF = ~F (element 255 never forced)
    const unsigned long long NF0 = ~(B40 | (B20 & ~(S0 ^ Sp0)));
    const unsigned long long NF1 = ~(B41 | (B21 & ~(S1 ^ Sp1)));
    const unsigned long long NF2 = ~(B42 | (B22 & ~(S2 ^ Sp2)));
    const unsigned long long NF3 = ~((B43 | (B23 & ~(S3 ^ Sp3))) & 0x7FFFFFFFFFFFFFFFull);
    // post-jump trigger masks by ENTRY direction (threshold: same-dir 2lam, opposite 4lam)
    const unsigned long long FNn0 = (S0 & B20) | (~S0 & B40);
    const unsigned long long FNn1 = (S1 & B21) | (~S1 & B41);
    const unsigned long long FNn2 = (S2 & B22) | (~S2 & B42);
    const unsigned long long FNn3 = (S3 & B23) | (~S3 & B43);
    const unsigned long long FNp0 = (~S0 & B20) | (S0 & B40);
    const unsigned long long FNp1 = (~S1 & B21) | (S1 & B41);
    const unsigned long long FNp2 = (~S2 & B22) | (S2 & B42);
    const unsigned long long FNp3 = (~S3 & B23) | (S3 & B43);
    const int initFF = (int)(B40 & 1ull);        // conservative (|d0|>4lam => forced first jump)

    // first non-forced element >= jmin (fast path: same word)
    auto firstnf = [&](int jmin) -> int {
        const int w = jmin >> 6;
        unsigned long long m = sel4(NF0, NF1, NF2, NF3, w) >> (jmin & 63);
        if (m) return jmin + (int)__builtin_ctzll(m);
        unsigned long long m1 = (w < 1) ? NF1 : 0ull;
        unsigned long long m2 = (w < 2) ? NF2 : 0ull;
        if (m1) return 64 + (int)__builtin_ctzll(m1);
        if (m2) return 128 + (int)__builtin_ctzll(m2);
        return 192 + (int)__builtin_ctzll(NF3);  // NF3 bit63 always set -> reachable & nonzero
    };

    auto trigbit = [&](int kk, int neg) -> int {
        const int w = kk >> 6;
        const unsigned long long m = neg ? sel4(FNn0, FNn1, FNn2, FNn3, w)
                                         : sel4(FNp0, FNp1, FNp2, FNp3, w);
        return (int)((m >> (kk & 63)) & 1ull);
    };

    // ---- serial state ----
    int k = 0, k0 = 0, km = 0, kp = 0;
    float umin = lam, umax = mlam;
    const float v0 = rlane(v.r0, 0);
    float vmin = v0 - lam, vmax = v0 + lam;
    float flen = 1.0f;                  // = k - k0 + 1
    float rnext = 0.5f;                 // invariant: rnext == rcp(flen + 1)
    float vn1 = rlane(vnx.r0, 0);       // v[k+1]
    int guard = 0;

    // pre: standard-fresh at k (=k0=km=kp), next jump forced, k <= N-2.
    // EXIT direction = sign(d[k]) is looked up here (NOT the entry direction).
    auto fastfwd = [&]() {
        const int K1 = firstnf(k + 1);                        // first non-forced j > k (<= 255)
        const int sneg = (int)((sel4(S0, S1, S2, S3, k >> 6) >> (k & 63)) & 1ull); // sign(d[k])
        flushseg(o, k, k, sneg ? vmin : vmax, lane);          // first run element
        if (K1 > k + 1) {                                     // (k, K1-1]: closed-form e[j]
            const int lo = k + 1;
            const unsigned len = (unsigned)(K1 - 1 - lo);
            const int base = lane - lo;
            o.r0 = ((unsigned)(base      ) <= len) ? e.r0 : o.r0;
            o.r1 = ((unsigned)(base + 64 ) <= len) ? e.r1 : o.r1;
            o.r2 = ((unsigned)(base + 128) <= len) ? e.r2 : o.r2;
            o.r3 = ((unsigned)(base + 192) <= len) ? e.r3 : o.r3;
        }
        k = K1; k0 = K1; km = K1; kp = K1;                    // fresh at K1, entry sign = S[K1-1]
        vmin = dfetch(g, K1);                                 // = v[K1] - lam - sl[K1-1]
        vmax = vmin + twolam;
        umin = lam; umax = mlam;
        flen = 1.0f; rnext = 0.5f;
        vn1 = dfetch(vnx, K1);                                // shares lane/sel calc with g fetch
    };

    auto do_step = [&]() {
        const float un = umin + vn1 - vmin;
        const float ux = umax + vn1 - vmax;
        const bool neg = un < mlam;
        const bool pos = ux > lam;
        // speculative FF-trigger bits for the fresh landing spot k+1 (off-chain SALU)
        const int wn = (k + 1) >> 6, bn = (k + 1) & 63;
        const int tn = (int)((sel4(FNn0, FNn1, FNn2, FNn3, wn) >> bn) & 1ull);
        const int tp = (int)((sel4(FNp0, FNp1, FNp2, FNp3, wn) >> bn) & 1ull);
        if (__builtin_expect((int)(neg | pos), 1)) {          // JUMP
            const float fval = neg ? vmin : vmax;
            const int   fhi  = neg ? km : kp;
            flushseg(o, k0, fhi, fval, lane);
            const int k0n = fhi + 1;
            float vstar;
            int trig;
            if (__builtin_expect((int)(k0n <= k), 0)) {       // rewind (rare)
                vstar = dfetch(v, k0n);
                trig = trigbit(k0n, (int)neg);
            } else {                                          // fresh: renames + precomputed trig
                vstar = vn1;
                trig = neg ? tn : tp;
            }
            k = k0n; k0 = k0n; km = k0n; kp = k0n;
            vmin = neg ? vstar : vstar - twolam;
            vmax = vmin + twolam;
            umin = lam; umax = mlam;
            flen = 1.0f; rnext = 0.5f;
            if (k < N - 1 && trig) {
                fastfwd();                                    // run of guaranteed jumps
            } else {
                vn1 = dfetch(vnx, k);                         // = v[k+1] (total, clamp-free)
            }
        } else {                                              // no jump (predicated)
            k++;
            const float r = rnext;                            // = rcp(k - k0 + 1), precomputed
            flen += 1.0f;
            const bool cmin = (un >= lam);
            const bool cmax = (ux <= mlam);
            vmin = cmin ? fmaf(un - lam, r, vmin) : vmin;
            km   = cmin ? k : km;
            umin = cmin ? lam : un;
            vmax = cmax ? fmaf(ux + lam, r, vmax) : vmax;
            kp   = cmax ? k : kp;
            umax = cmax ? mlam : ux;
            vn1 = dfetch(vnx, k);                             // = v[k+1] (total, clamp-free)
            rnext = __builtin_amdgcn_rcpf(flen + 1.0f);       // off-chain for next step
        }
    };

    if (initFF) fastfwd();

    for (;;) {
        while (k < N - 1) {
            if (++guard > 2000) return; // provably terminates; belt+suspenders
            do_step();
            if (k >= N - 1) break;
            do_step();
        }
        // boundary resolution at k == N-1 (verbatim semantics from verified R2/R6)
        for (;;) {
            if (++guard > 4000) return;
            if (umin < 0.0f) {
                flushseg(o, k0, km, vmin, lane);
                k0 = km + 1;
                if (k0 > N - 1) return;
                km = k = k0;
                vmin = dfetch(v, k0);
                umin = lam;
                umax = vmin + lam - vmax;
                flen = 1.0f;
            } else if (umax > 0.0f) {
                flushseg(o, k0, kp, vmax, lane);
                k0 = kp + 1;
                if (k0 > N - 1) return;
                kp = k = k0;
                vmax = dfetch(v, k0);
                umax = mlam;
                umin = vmax - lam - vmin;
                flen = 1.0f;
            } else {
                vmin += umin / flen;
                flushseg(o, k0, k, vmin, lane);
                return;
            }
            if (k != N - 1) break;
        }
        rnext = 0.5f;                                         // flen == 1 here
        vn1 = dfetch(vnx, k);                                 // = v[k+1]
    }
}

// Packed-slot grid barrier over L2-bypassing data: NO cache wb/inv, ordering only.
__device__ __forceinline__ void gridbar1(unsigned long long* slots, unsigned seq,
                                         unsigned accfill, int t) {
    __syncthreads();
    __builtin_amdgcn_s_waitcnt(0);                            // vmcnt(0) lgkmcnt(0): stores drained
    if (t == 0)
        __hip_atomic_store(&slots[blockIdx.x * SLOTSTRIDE],
                           ((unsigned long long)accfill << 32) | (unsigned long long)seq,
                           __ATOMIC_RELAXED, __HIP_MEMORY_SCOPE_AGENT);
    if (t < 64) {
        for (;;) {
            unsigned long long f = __hip_atomic_load(&slots[t * SLOTSTRIDE],
                                                     __ATOMIC_RELAXED, __HIP_MEMORY_SCOPE_AGENT);
            if (__all((int)((unsigned)f >= seq))) break;
        }
    }
    __builtin_amdgcn_s_waitcnt(0);
    __syncthreads();
}

// barrier 2: payload-carrying; computes the grid-wide convergence decision from
// the poll's final values (free — no separate round trip).
__device__ __forceinline__ void gridbar2(unsigned long long* slots, unsigned seq,
                                         unsigned acc, int t, int* s_dec) {
    __syncthreads();
    __builtin_amdgcn_s_waitcnt(0);
    if (t == 0)
        __hip_atomic_store(&slots[blockIdx.x * SLOTSTRIDE],
                           ((unsigned long long)acc << 32) | (unsigned long long)seq,
                           __ATOMIC_RELAXED, __HIP_MEMORY_SCOPE_AGENT);
    if (t < 64) {
        unsigned long long f;
        for (;;) {
            f = __hip_atomic_load(&slots[t * SLOTSTRIDE],
                                  __ATOMIC_RELAXED, __HIP_MEMORY_SCOPE_AGENT);
            if (__all((int)((unsigned)f >= seq))) break;
        }
        unsigned a = (unsigned)(f >> 32);
        #pragma unroll
        for (int off = 32; off > 0; off >>= 1) {
            unsigned aa = __shfl_xor(a, off);
            a = (aa > a) ? aa : a;                            // acc>=0: uint order == float order
        }
        if (t == 0) *s_dec = (__uint_as_float(a) < TOL) ? 1 : 0;
    }
    __builtin_amdgcn_s_waitcnt(0);
    __syncthreads();
}

// Douglas-Rachford TV2D. Wave w of block b owns column (4b+w) in phase 1 and row
// (4b+w) in phase 2. Coalesced 16B sc1 staging loads + LDS transpose; all y/xw
// traffic L2-bypassing so barriers need no cache maintenance.
__global__ __launch_bounds__(NT) void tv2d_coop(const float* __restrict__ X,
                                                float* __restrict__ xw,     // = d_out
                                                float* __restrict__ y,      // holds yT
                                                unsigned long long* __restrict__ slots)
{
    const int t = threadIdx.x;
    const int lane = t & 63;
    const int wave = t >> 6;
    const int line = blockIdx.x * NLINE + wave;
    const int col4 = 4 * blockIdx.x;             // block's 4-column / 4-row group
    __shared__ float tile[N * 5];                // transpose tile, stride-5 padded
    __shared__ unsigned s_acc;
    __shared__ int s_dec;
    if (t == 0) s_acc = 0u;

    Dist p = {0.f, 0.f, 0.f, 0.f};
    Dist q = {0.f, 0.f, 0.f, 0.f};
    unsigned accprev = 0u;                       // block's acc from previous iteration

    for (int it = 0; it < MAXIT; ++it) {
        // ---- column phase: y = prox(x + p) on column `line`; p = v - y ----
        const float* xs = (it == 0) ? X : xw;
        const float4 xc = gload4(xs + t * N + col4);   // 16B L2-bypass load
        tile[t * 5 + 0] = xc.x;                 // transpose deposit: tile[row][c]
        tile[t * 5 + 1] = xc.y;
        tile[t * 5 + 2] = xc.z;
        tile[t * 5 + 3] = xc.w;
        __syncthreads();
        Dist v, o;
        v.r0 = tile[(lane      ) * 5 + wave] + p.r0;   // column `line` from LDS
        v.r1 = tile[(lane + 64 ) * 5 + wave] + p.r1;
        v.r2 = tile[(lane + 128) * 5 + wave] + p.r2;
        v.r3 = tile[(lane + 192) * 5 + wave] + p.r3;
        tv1d_scan(v, o, lane);
        p.r0 = v.r0 - o.r0;  p.r1 = v.r1 - o.r1;
        p.r2 = v.r2 - o.r2;  p.r3 = v.r3 - o.r3;
        float* yt = y + line * N;               // y stored TRANSPOSED -> coalesced
        gstore(yt + lane,       o.r0);
        gstore(yt + lane + 64,  o.r1);
        gstore(yt + lane + 128, o.r2);
        gstore(yt + lane + 192, o.r3);
        gridbar1(slots, 2u * (unsigned)it + 1u, accprev, t);

        // ---- row phase: x2 = prox(y + q) on row `line`; q = v - x2; acc = max|y-x2| ----
        const float4 yc = gload4(y + t * N + col4);    // 16B L2-bypass load
        tile[t * 5 + 0] = yc.x;                 // tile[j][c] = y[col4+c][j]
        tile[t * 5 + 1] = yc.y;
        tile[t * 5 + 2] = yc.z;
        tile[t * 5 + 3] = yc.w;
        __syncthreads();
        float y0 = tile[(lane      ) * 5 + wave];      // row `line` elements
        float y1 = tile[(lane + 64 ) * 5 + wave];
        float y2 = tile[(lane + 128) * 5 + wave];
        float y3 = tile[(lane + 192) * 5 + wave];
        Dist w, o2;
        w.r0 = y0 + q.r0;
        w.r1 = y1 + q.r1;
        w.r2 = y2 + q.r2;
        w.r3 = y3 + q.r3;
        tv1d_scan(w, o2, lane);
        float d0 = y0 - o2.r0;    // y - x2
        float d1 = y1 - o2.r1;
        float d2 = y2 - o2.r2;
        float d3 = y3 - o2.r3;
        q.r0 = w.r0 - o2.r0;  q.r1 = w.r1 - o2.r1;
        q.r2 = w.r2 - o2.r2;  q.r3 = w.r3 - o2.r3;
        float* xr = xw + line * N;              // row-major, coalesced
        gstore(xr + lane,       o2.r0);
        gstore(xr + lane + 64,  o2.r1);
        gstore(xr + lane + 128, o2.r2);
        gstore(xr + lane + 192, o2.r3);

        float am = fmaxf(fmaxf(fabsf(d0), fabsf(d1)), fmaxf(fabsf(d2), fabsf(d3)));
        #pragma unroll
        for (int off = 32; off > 0; off >>= 1)
            am = fmaxf(am, __shfl_xor(am, off));
        if (lane == 0) atomicMax(&s_acc, __float_as_uint(am));   // LDS atomic, 4/block
        __syncthreads();                                          // s_acc complete
        const unsigned ba = s_acc;                                // everyone reads before reset

        if (it == MAXIT - 1) break;             // nothing after the last row phase is read

        // ---- barrier 2: packed {acc, seq}; decision computed in-poll ----
        gridbar2(slots, 2u * (unsigned)it + 2u, ba, t, &s_dec);   // leading syncthreads orders ba reads
        if (t == 0) s_acc = 0u;                 // safe: next atomicMax is after gridbar1 of it+1
        if (s_dec) break;                       // xw holds x2 of `it` (reference output)
        accprev = ba;
    }
}

extern "C" void kernel_launch(void* const* d_in, const int* in_sizes, int n_in,
                              void* d_out, int out_size, void* d_ws, size_t ws_size,
                              hipStream_t stream) {
    const float* X = (const float*)d_in[0];
    float* xw = (float*)d_out;
    float* y = (float*)d_ws;
    unsigned long long* slots = (unsigned long long*)((char*)d_ws + (size_t)N * N * sizeof(float));
    // zero the slot array (64 slots x 128 B) before the kernel (capture-legal)
    (void)hipMemsetAsync((void*)slots, 0, NB * SLOTSTRIDE * sizeof(unsigned long long), stream);
    void* args[] = { (void*)&X, (void*)&xw, (void*)&y, (void*)&slots };
    (void)hipLaunchCooperativeKernel((void*)tv2d_coop, dim3(NB), dim3(NT), args, 0, stream);
}

// Round 21
// 279.086 us; speedup vs baseline: 1.2256x; 1.0166x over previous
//
#include <hip/hip_runtime.h>

#define N 256
#define NLINE 4               // lines (waves) per block
#define NB (N / NLINE)        // 64 blocks
#define NT (NLINE * 64)       // 256 threads
#define LAM 0.05f             // step = ALPHA/2
#define TWOLAM (2.0f * LAM)
#define FOURLAM (4.0f * LAM)
#define MAXIT 35
#define TOL 0.01f
#define SLOTSTRIDE 16         // uint64 elements -> 128 B per block slot (own L3 line)

// broadcast-read one lane's register (lane index is wave-uniform -> v_readlane)
__device__ __forceinline__ float rlane(float v, int lane) {
    return __int_as_float(__builtin_amdgcn_readlane(__float_as_int(v), lane));
}

// agent-scope (L2-bypassing) scalar access for cross-block-communicated arrays.
__device__ __forceinline__ void gstore(float* p, float v) {
    __hip_atomic_store(p, v, __ATOMIC_RELAXED, __HIP_MEMORY_SCOPE_AGENT);
}
// 16-byte L2-bypassing load (sc0 sc1 = coherent scope, L3-served — never caches
// in L2, so the no-cache-maintenance barrier remains correct).
__device__ __forceinline__ float4 gload4(const float* p) {
    float4 r;
    asm volatile("global_load_dwordx4 %0, %1, off sc0 sc1\n\ts_waitcnt vmcnt(0)"
                 : "=&v"(r) : "v"(p) : "memory");
    return r;
}

// 256-float line distributed over the wave: element k lives in lane (k&63), reg (k>>6)
// -> ballot words are CONTIGUOUS 64-element spans (word w = elements 64w..64w+63)
struct Dist { float r0, r1, r2, r3; };

// branchless fetch: 4 independent readlanes + 2 uniform selects
__device__ __forceinline__ float dfetch(const Dist& d, int k) {
    const int lane = k & 63;
    const int sel = k >> 6;
    float a = rlane(d.r0, lane);
    float b = rlane(d.r1, lane);
    float c = rlane(d.r2, lane);
    float e = rlane(d.r3, lane);
    float ab = (sel & 1) ? b : a;
    float ce = (sel & 1) ? e : c;
    return (sel & 2) ? ce : ab;
}

// O(1) segment flush: o[j] = val for j in [lo, hi]; element j of reg r = 64r + lane
__device__ __forceinline__ void flushseg(Dist& o, int lo, int hi, float val, int lane) {
    const unsigned len = (unsigned)(hi - lo);
    const int base = lane - lo;
    o.r0 = ((unsigned)(base      ) <= len) ? val : o.r0;
    o.r1 = ((unsigned)(base + 64 ) <= len) ? val : o.r1;
    o.r2 = ((unsigned)(base + 128) <= len) ? val : o.r2;
    o.r3 = ((unsigned)(base + 192) <= len) ? val : o.r3;
}

// scalar 4-way select of a 64-bit mask (s_cselect_b64)
__device__ __forceinline__ unsigned long long sel4(unsigned long long a, unsigned long long b,
                                                   unsigned long long c, unsigned long long d, int r) {
    unsigned long long ab = (r & 1) ? b : a;
    unsigned long long cd = (r & 1) ? d : c;
    return (r & 2) ? cd : ab;
}

// Condat's exact 1D TV prox (verified R14 structure; guard counters removed —
// termination is provable: every jump/FF strictly advances k0, every no-jump
// strictly advances k, and the boundary loop strictly advances k0).
__device__ void tv1d_scan(const Dist& v, Dist& o, const int lane)
{
    const float lam = LAM, mlam = -LAM, twolam = TWOLAM;

    // ---- per-scan precompute (vectorized) ----
    Dist vnx;                                    // vnx[j] = v[j+1] for j<255; vnx[255] = v[255]
    {
        float a0 = __shfl_down(v.r0, 1), a1 = __shfl_down(v.r1, 1);
        float a2 = __shfl_down(v.r2, 1), a3 = __shfl_down(v.r3, 1);
        const bool hi = (lane == 63);
        vnx.r0 = hi ? rlane(v.r1, 0) : a0;
        vnx.r1 = hi ? rlane(v.r2, 0) : a1;
        vnx.r2 = hi ? rlane(v.r3, 0) : a2;
        vnx.r3 = hi ? v.r3 : a3;                 // element 255 -> v[255] (safe total fetch)
    }
    Dist d;
    d.r0 = vnx.r0 - v.r0;  d.r1 = vnx.r1 - v.r1;
    d.r2 = vnx.r2 - v.r2;  d.r3 = vnx.r3 - v.r3;
    const unsigned lambits = __float_as_uint(lam);
    Dist sl;                                     // sl[j] = sign(d[j]) * lam
    sl.r0 = __uint_as_float((__float_as_uint(d.r0) & 0x80000000u) | lambits);
    sl.r1 = __uint_as_float((__float_as_uint(d.r1) & 0x80000000u) | lambits);
    sl.r2 = __uint_as_float((__float_as_uint(d.r2) & 0x80000000u) | lambits);
    sl.r3 = __uint_as_float((__float_as_uint(d.r3) & 0x80000000u) | lambits);
    Dist slp;                                    // slp[j] = sl[j-1], slp[0] = 0
    {
        float b0 = __shfl_up(sl.r0, 1), b1 = __shfl_up(sl.r1, 1);
        float b2 = __shfl_up(sl.r2, 1), b3 = __shfl_up(sl.r3, 1);
        const bool lo = (lane == 0);
        slp.r0 = lo ? 0.0f : b0;
        slp.r1 = lo ? rlane(sl.r0, 63) : b1;
        slp.r2 = lo ? rlane(sl.r1, 63) : b2;
        slp.r3 = lo ? rlane(sl.r2, 63) : b3;
    }
    Dist e, g;                                   // e[j] = v[j]+sl[j]-slp[j]; g[j] = v[j]-lam-slp[j]
    {
        float t0 = v.r0 - slp.r0, t1 = v.r1 - slp.r1, t2 = v.r2 - slp.r2, t3 = v.r3 - slp.r3;
        e.r0 = t0 + sl.r0;  e.r1 = t1 + sl.r1;  e.r2 = t2 + sl.r2;  e.r3 = t3 + sl.r3;
        g.r0 = t0 - lam;    g.r1 = t1 - lam;    g.r2 = t2 - lam;    g.r3 = t3 - lam;
    }
    const unsigned long long S0 = __ballot(d.r0 < 0.0f);
    const unsigned long long S1 = __ballot(d.r1 < 0.0f);
    const unsigned long long S2 = __ballot(d.r2 < 0.0f);
    const unsigned long long S3 = __ballot(d.r3 < 0.0f);
    const unsigned long long B20 = __ballot(fabsf(d.r0) > TWOLAM);
    const unsigned long long B21 = __ballot(fabsf(d.r1) > TWOLAM);
    const unsigned long long B22 = __ballot(fabsf(d.r2) > TWOLAM);
    const unsigned long long B23 = __ballot(fabsf(d.r3) > TWOLAM);
    const unsigned long long B40 = __ballot(fabsf(d.r0) > FOURLAM);
    const unsigned long long B41 = __ballot(fabsf(d.r1) > FOURLAM);
    const unsigned long long B42 = __ballot(fabsf(d.r2) > FOURLAM);
    const unsigned long long B43 = __ballot(fabsf(d.r3) > FOURLAM);
    // Sprev shifts S by one element across contiguous words
    const unsigned long long Sp0 = (S0 << 1);
    const unsigned long long Sp1 = (S1 << 1) | (S0 >> 63);
    const unsigned long long Sp2 = (S2 << 1) | (S1 >> 63);
    const unsigned long long Sp3 = (S3 << 1) | (S2 >> 63);
    // run-continuation: F = B4 | (B2 & same-sign-as-prev); NF = ~F (element 255 never forced)
    const unsigned long long NF0 = ~(B40 | (B20 & ~(S0 ^ Sp0)));
    const unsigned long long NF1 = ~(B41 | (B21 & ~(S1 ^ Sp1)));
    const unsigned long long NF2 = ~(B42 | (B22 & ~(S2 ^ Sp2)));
    const unsigned long long NF3 = ~((B43 | (B23 & ~(S3 ^ Sp3))) & 0x7FFFFFFFFFFFFFFFull);
    // post-jump trigger masks by ENTRY direction (threshold: same-dir 2lam, opposite 4lam)
    const unsigned long long FNn0 = (S0 & B20) | (~S0 & B40);
    const unsigned long long FNn1 = (S1 & B21) | (~S1 & B41);
    const unsigned long long FNn2 = (S2 & B22) | (~S2 & B42);
    const unsigned long long FNn3 = (S3 & B23) | (~S3 & B43);
    const unsigned long long FNp0 = (~S0 & B20) | (S0 & B40);
    const unsigned long long FNp1 = (~S1 & B21) | (S1 & B41);
    const unsigned long long FNp2 = (~S2 & B22) | (S2 & B42);
    const unsigned long long FNp3 = (~S3 & B23) | (S3 & B43);
    const int initFF = (int)(B40 & 1ull);        // conservative (|d0|>4lam => forced first jump)

    // first non-forced element >= jmin (fast path: same word)
    auto firstnf = [&](int jmin) -> int {
        const int w = jmin >> 6;
        unsigned long long m = sel4(NF0, NF1, NF2, NF3, w) >> (jmin & 63);
        if (m) return jmin + (int)__builtin_ctzll(m);
        unsigned long long m1 = (w < 1) ? NF1 : 0ull;
        unsigned long long m2 = (w < 2) ? NF2 : 0ull;
        if (m1) return 64 + (int)__builtin_ctzll(m1);
        if (m2) return 128 + (int)__builtin_ctzll(m2);
        return 192 + (int)__builtin_ctzll(NF3);  // NF3 bit63 always set -> reachable & nonzero
    };

    auto trigbit = [&](int kk, int neg) -> int {
        const int w = kk >> 6;
        const unsigned long long m = neg ? sel4(FNn0, FNn1, FNn2, FNn3, w)
                                         : sel4(FNp0, FNp1, FNp2, FNp3, w);
        return (int)((m >> (kk & 63)) & 1ull);
    };

    // ---- serial state ----
    int k = 0, k0 = 0, km = 0, kp = 0;
    float umin = lam, umax = mlam;
    const float v0 = rlane(v.r0, 0);
    float vmin = v0 - lam, vmax = v0 + lam;
    float flen = 1.0f;                  // = k - k0 + 1
    float rnext = 0.5f;                 // invariant: rnext == rcp(flen + 1)
    float vn1 = rlane(vnx.r0, 0);       // v[k+1]

    // pre: standard-fresh at k (=k0=km=kp), next jump forced, k <= N-2.
    // EXIT direction = sign(d[k]) is looked up here (NOT the entry direction).
    auto fastfwd = [&]() {
        const int K1 = firstnf(k + 1);                        // first non-forced j > k (<= 255)
        const int sneg = (int)((sel4(S0, S1, S2, S3, k >> 6) >> (k & 63)) & 1ull); // sign(d[k])
        flushseg(o, k, k, sneg ? vmin : vmax, lane);          // first run element
        if (K1 > k + 1) {                                     // (k, K1-1]: closed-form e[j]
            const int lo = k + 1;
            const unsigned len = (unsigned)(K1 - 1 - lo);
            const int base = lane - lo;
            o.r0 = ((unsigned)(base      ) <= len) ? e.r0 : o.r0;
            o.r1 = ((unsigned)(base + 64 ) <= len) ? e.r1 : o.r1;
            o.r2 = ((unsigned)(base + 128) <= len) ? e.r2 : o.r2;
            o.r3 = ((unsigned)(base + 192) <= len) ? e.r3 : o.r3;
        }
        k = K1; k0 = K1; km = K1; kp = K1;                    // fresh at K1, entry sign = S[K1-1]
        vmin = dfetch(g, K1);                                 // = v[K1] - lam - sl[K1-1]
        vmax = vmin + twolam;
        umin = lam; umax = mlam;
        flen = 1.0f; rnext = 0.5f;
        vn1 = dfetch(vnx, K1);                                // shares lane/sel calc with g fetch
    };

    auto do_step = [&]() {
        const float un = umin + vn1 - vmin;
        const float ux = umax + vn1 - vmax;
        const bool neg = un < mlam;
        const bool pos = ux > lam;
        // speculative FF-trigger bits for the fresh landing spot k+1 (off-chain SALU)
        const int wn = (k + 1) >> 6, bn = (k + 1) & 63;
        const int tn = (int)((sel4(FNn0, FNn1, FNn2, FNn3, wn) >> bn) & 1ull);
        const int tp = (int)((sel4(FNp0, FNp1, FNp2, FNp3, wn) >> bn) & 1ull);
        if (__builtin_expect((int)(neg | pos), 1)) {          // JUMP
            const float fval = neg ? vmin : vmax;
            const int   fhi  = neg ? km : kp;
            flushseg(o, k0, fhi, fval, lane);
            const int k0n = fhi + 1;
            float vstar;
            int trig;
            if (__builtin_expect((int)(k0n <= k), 0)) {       // rewind (rare)
                vstar = dfetch(v, k0n);
                trig = trigbit(k0n, (int)neg);
            } else {                                          // fresh: renames + precomputed trig
                vstar = vn1;
                trig = neg ? tn : tp;
            }
            k = k0n; k0 = k0n; km = k0n; kp = k0n;
            vmin = neg ? vstar : vstar - twolam;
            vmax = vmin + twolam;
            umin = lam; umax = mlam;
            flen = 1.0f; rnext = 0.5f;
            if (k < N - 1 && trig) {
                fastfwd();                                    // run of guaranteed jumps
            } else {
                vn1 = dfetch(vnx, k);                         // = v[k+1] (total, clamp-free)
            }
        } else {                                              // no jump (predicated)
            k++;
            const float r = rnext;                            // = rcp(k - k0 + 1), precomputed
            flen += 1.0f;
            const bool cmin = (un >= lam);
            const bool cmax = (ux <= mlam);
            vmin = cmin ? fmaf(un - lam, r, vmin) : vmin;
            km   = cmin ? k : km;
            umin = cmin ? lam : un;
            vmax = cmax ? fmaf(ux + lam, r, vmax) : vmax;
            kp   = cmax ? k : kp;
            umax = cmax ? mlam : ux;
            vn1 = dfetch(vnx, k);                             // = v[k+1] (total, clamp-free)
            rnext = __builtin_amdgcn_rcpf(flen + 1.0f);       // off-chain for next step
        }
    };

    if (initFF) fastfwd();

    for (;;) {
        while (k < N - 1) {
            do_step();
            if (k >= N - 1) break;
            do_step();
        }
        // boundary resolution at k == N-1 (verbatim semantics from verified R2/R6)
        for (;;) {
            if (umin < 0.0f) {
                flushseg(o, k0, km, vmin, lane);
                k0 = km + 1;
                if (k0 > N - 1) return;
                km = k = k0;
                vmin = dfetch(v, k0);
                umin = lam;
                umax = vmin + lam - vmax;
                flen = 1.0f;
            } else if (umax > 0.0f) {
                flushseg(o, k0, kp, vmax, lane);
                k0 = kp + 1;
                if (k0 > N - 1) return;
                kp = k = k0;
                vmax = dfetch(v, k0);
                umax = mlam;
                umin = vmax - lam - vmin;
                flen = 1.0f;
            } else {
                vmin += umin / flen;
                flushseg(o, k0, k, vmin, lane);
                return;
            }
            if (k != N - 1) break;
        }
        rnext = 0.5f;                                         // flen == 1 here
        vn1 = dfetch(vnx, k);                                 // = v[k+1]
    }
}

// Packed-slot grid barrier over L2-bypassing data: NO cache wb/inv, ordering only.
// Poll is software-pipelined: probe n+1 issues before probe n's ballot resolves.
__device__ __forceinline__ void gridbar1(unsigned long long* slots, unsigned seq,
                                         unsigned accfill, int t) {
    __syncthreads();
    __builtin_amdgcn_s_waitcnt(0);                            // y-stores drained before flag store
    if (t == 0)
        __hip_atomic_store(&slots[blockIdx.x * SLOTSTRIDE],
                           ((unsigned long long)accfill << 32) | (unsigned long long)seq,
                           __ATOMIC_RELAXED, __HIP_MEMORY_SCOPE_AGENT);
    if (t < 64) {
        unsigned long long f = __hip_atomic_load(&slots[t * SLOTSTRIDE],
                                                 __ATOMIC_RELAXED, __HIP_MEMORY_SCOPE_AGENT);
        for (;;) {
            unsigned long long fn = __hip_atomic_load(&slots[t * SLOTSTRIDE],
                                                      __ATOMIC_RELAXED, __HIP_MEMORY_SCOPE_AGENT);
            if (__all((int)((unsigned)f >= seq))) break;      // check overlaps next probe
            f = fn;
        }
    }
    __syncthreads();
}

// barrier 2: payload-carrying; computes the grid-wide convergence decision from
// the poll's final values (free — no separate round trip).
__device__ __forceinline__ void gridbar2(unsigned long long* slots, unsigned seq,
                                         unsigned acc, int t, int* s_dec) {
    __syncthreads();
    __builtin_amdgcn_s_waitcnt(0);                            // x2-stores drained before flag store
    if (t == 0)
        __hip_atomic_store(&slots[blockIdx.x * SLOTSTRIDE],
                           ((unsigned long long)acc << 32) | (unsigned long long)seq,
                           __ATOMIC_RELAXED, __HIP_MEMORY_SCOPE_AGENT);
    if (t < 64) {
        unsigned long long f = __hip_atomic_load(&slots[t * SLOTSTRIDE],
                                                 __ATOMIC_RELAXED, __HIP_MEMORY_SCOPE_AGENT);
        for (;;) {
            unsigned long long fn = __hip_atomic_load(&slots[t * SLOTSTRIDE],
                                                      __ATOMIC_RELAXED, __HIP_MEMORY_SCOPE_AGENT);
            if (__all((int)((unsigned)f >= seq))) break;
            f = fn;
        }
        unsigned a = (unsigned)(f >> 32);
        #pragma unroll
        for (int off = 32; off > 0; off >>= 1) {
            unsigned aa = __shfl_xor(a, off);
            a = (aa > a) ? aa : a;                            // acc>=0: uint order == float order
        }
        if (t == 0) *s_dec = (__uint_as_float(a) < TOL) ? 1 : 0;
    }
    __syncthreads();
}

// Douglas-Rachford TV2D. Wave w of block b owns column (4b+w) in phase 1 and row
// (4b+w) in phase 2. Coalesced 16B sc1 staging loads + LDS transpose; all y/xw
// traffic L2-bypassing so barriers need no cache maintenance.
__global__ __launch_bounds__(NT) void tv2d_coop(const float* __restrict__ X,
                                                float* __restrict__ xw,     // = d_out
                                                float* __restrict__ y,      // holds yT
                                                unsigned long long* __restrict__ slots)
{
    const int t = threadIdx.x;
    const int lane = t & 63;
    const int wave = t >> 6;
    const int line = blockIdx.x * NLINE + wave;
    const int col4 = 4 * blockIdx.x;             // block's 4-column / 4-row group
    __shared__ float tile[N * 5];                // transpose tile, stride-5 padded
    __shared__ unsigned s_acc;
    __shared__ int s_dec;
    if (t == 0) s_acc = 0u;

    Dist p = {0.f, 0.f, 0.f, 0.f};
    Dist q = {0.f, 0.f, 0.f, 0.f};
    unsigned accprev = 0u;                       // block's acc from previous iteration

    for (int it = 0; it < MAXIT; ++it) {
        // ---- column phase: y = prox(x + p) on column `line`; p = v - y ----
        const float* xs = (it == 0) ? X : xw;
        const float4 xc = gload4(xs + t * N + col4);   // 16B L2-bypass load
        tile[t * 5 + 0] = xc.x;                 // transpose deposit: tile[row][c]
        tile[t * 5 + 1] = xc.y;
        tile[t * 5 + 2] = xc.z;
        tile[t * 5 + 3] = xc.w;
        __syncthreads();
        Dist v, o;
        v.r0 = tile[(lane      ) * 5 + wave] + p.r0;   // column `line` from LDS
        v.r1 = tile[(lane + 64 ) * 5 + wave] + p.r1;
        v.r2 = tile[(lane + 128) * 5 + wave] + p.r2;
        v.r3 = tile[(lane + 192) * 5 + wave] + p.r3;
        tv1d_scan(v, o, lane);
        p.r0 = v.r0 - o.r0;  p.r1 = v.r1 - o.r1;
        p.r2 = v.r2 - o.r2;  p.r3 = v.r3 - o.r3;
        float* yt = y + line * N;               // y stored TRANSPOSED -> coalesced
        gstore(yt + lane,       o.r0);
        gstore(yt + lane + 64,  o.r1);
        gstore(yt + lane + 128, o.r2);
        gstore(yt + lane + 192, o.r3);
        gridbar1(slots, 2u * (unsigned)it + 1u, accprev, t);

        // ---- row phase: x2 = prox(y + q) on row `line`; q = v - x2; acc = max|y-x2| ----
        const float4 yc = gload4(y + t * N + col4);    // 16B L2-bypass load
        tile[t * 5 + 0] = yc.x;                 // tile[j][c] = y[col4+c][j]
        tile[t * 5 + 1] = yc.y;
        tile[t * 5 + 2] = yc.z;
        tile[t * 5 + 3] = yc.w;
        __syncthreads();
        float y0 = tile[(lane      ) * 5 + wave];      // row `line` elements
        float y1 = tile[(lane + 64 ) * 5 + wave];
        float y2 = tile[(lane + 128) * 5 + wave];
        float y3 = tile[(lane + 192) * 5 + wave];
        Dist w, o2;
        w.r0 = y0 + q.r0;
        w.r1 = y1 + q.r1;
        w.r2 = y2 + q.r2;
        w.r3 = y3 + q.r3;
        tv1d_scan(w, o2, lane);
        float d0 = y0 - o2.r0;    // y - x2
        float d1 = y1 - o2.r1;
        float d2 = y2 - o2.r2;
        float d3 = y3 - o2.r3;
        q.r0 = w.r0 - o2.r0;  q.r1 = w.r1 - o2.r1;
        q.r2 = w.r2 - o2.r2;  q.r3 = w.r3 - o2.r3;
        float* xr = xw + line * N;              // row-major, coalesced
        gstore(xr + lane,       o2.r0);
        gstore(xr + lane + 64,  o2.r1);
        gstore(xr + lane + 128, o2.r2);
        gstore(xr + lane + 192, o2.r3);

        float am = fmaxf(fmaxf(fabsf(d0), fabsf(d1)), fmaxf(fabsf(d2), fabsf(d3)));
        #pragma unroll
        for (int off = 32; off > 0; off >>= 1)
            am = fmaxf(am, __shfl_xor(am, off));
        if (lane == 0) atomicMax(&s_acc, __float_as_uint(am));   // LDS atomic, 4/block
        __syncthreads();                                          // s_acc complete
        const unsigned ba = s_acc;                                // everyone reads before reset

        if (it == MAXIT - 1) break;             // nothing after the last row phase is read

        // ---- barrier 2: packed {acc, seq}; decision computed in-poll ----
        gridbar2(slots, 2u * (unsigned)it + 2u, ba, t, &s_dec);   // leading syncthreads orders ba reads
        if (t == 0) s_acc = 0u;                 // safe: next atomicMax is after gridbar1 of it+1
        if (s_dec) break;                       // xw holds x2 of `it` (reference output)
        accprev = ba;
    }
}

extern "C" void kernel_launch(void* const* d_in, const int* in_sizes, int n_in,
                              void* d_out, int out_size, void* d_ws, size_t ws_size,
                              hipStream_t stream) {
    const float* X = (const float*)d_in[0];
    float* xw = (float*)d_out;
    float* y = (float*)d_ws;
    unsigned long long* slots = (unsigned long long*)((char*)d_ws + (size_t)N * N * sizeof(float));
    // zero the slot array (64 slots x 128 B) before the kernel (capture-legal)
    (void)hipMemsetAsync((void*)slots, 0, NB * SLOTSTRIDE * sizeof(unsigned long long), stream);
    void* args[] = { (void*)&X, (void*)&xw, (void*)&y, (void*)&slots };
    (void)hipLaunchCooperativeKernel((void*)tv2d_coop, dim3(NB), dim3(NT), args, 0, stream);
}